// Round 1
// baseline (771.079 us; speedup 1.0000x reference)
//
#include <hip/hip_runtime.h>
#include <hip/hip_bf16.h>
#include <math.h>

// Problem constants (fixed by reference)
#define L_TOT 4097
#define BSZ 2
#define ROWS (BSZ*L_TOT)   // 8194
#define DMODEL 256
#define DINNER 512
#define DSTATE 16
#define NSEG 64
#define SEGLEN 65          // 64*65 = 4160 >= 4097

__device__ __forceinline__ float sigmoidf_(float v){ return 1.0f/(1.0f+__expf(-v)); }
__device__ __forceinline__ float siluf_(float v){ return v * sigmoidf_(v); }

// ---------------------------------------------------------------------------
// Generic f32 GEMM: C[M,N] = A[M,K] * W[N,K]^T   (64x64 tile, 4x4 per thread)
// MODE 0: A direct row-major.  MODE 1: A = x with token gather (skip cls row):
//         src_row = row + row/1024 + 1
// ---------------------------------------------------------------------------
template<int MODE>
__global__ __launch_bounds__(256) void gemm_f32(
    const float* __restrict__ A, const float* __restrict__ W,
    float* __restrict__ C, int M, int N, int K)
{
    __shared__ float As[16][68];
    __shared__ float Ws[16][68];
    const int tid = threadIdx.x;
    const int tx = tid & 15, ty = tid >> 4;
    const int n0 = blockIdx.x * 64;
    const int m0 = blockIdx.y * 64;
    float acc[4][4] = {};

    for (int k0 = 0; k0 < K; k0 += 16) {
        #pragma unroll
        for (int p = 0; p < 4; p++) {
            int r = p*16 + ty;
            int c = tx;
            int row = m0 + r;
            float av = 0.f;
            if (row < M) {
                long srow = row;
                if (MODE == 1) srow = row + row/1024 + 1;
                av = A[srow*(long)K + k0 + c];
            }
            As[c][r] = av;
            Ws[c][r] = W[(long)(n0 + r)*K + k0 + c];
        }
        __syncthreads();
        #pragma unroll
        for (int k = 0; k < 16; k++) {
            float4 a4 = *(const float4*)&As[k][ty*4];
            float4 w4 = *(const float4*)&Ws[k][tx*4];
            float av[4] = {a4.x, a4.y, a4.z, a4.w};
            float wv[4] = {w4.x, w4.y, w4.z, w4.w};
            #pragma unroll
            for (int i = 0; i < 4; i++)
                #pragma unroll
                for (int j = 0; j < 4; j++)
                    acc[i][j] += av[i]*wv[j];
        }
        __syncthreads();
    }
    #pragma unroll
    for (int i = 0; i < 4; i++) {
        int row = m0 + ty*4 + i;
        if (row < M) {
            float4 o = make_float4(acc[i][0], acc[i][1], acc[i][2], acc[i][3]);
            *(float4*)&C[(long)row*N + n0 + tx*4] = o;
        }
    }
}

// ---------------------------------------------------------------------------
// Patch rearrange + LayerNorm(256) + skip add; also the cls row (q==0).
// e_buf: [2048, 1024];  xx out: [2, 4097, 256]
// ---------------------------------------------------------------------------
__global__ __launch_bounds__(256) void rearrange_ln_cls(
    const float* __restrict__ e_buf, const float* __restrict__ x,
    const float* __restrict__ cls_w, const float* __restrict__ cls_b,
    const float* __restrict__ ln_g, const float* __restrict__ ln_b,
    const float* __restrict__ skip, float* __restrict__ xx)
{
    const int blk = blockIdx.x;           // 0..8193
    const int b = blk / L_TOT;
    const int q = blk % L_TOT;
    const int c = threadIdx.x;            // 0..255

    if (q == 0) {
        const float* xr = x + (long)b*1025*512;
        float acc = 0.f;
        for (int m = 0; m < 512; m++) acc += xr[m]*cls_w[c*512 + m];
        float v = acc + cls_b[c] + skip[((long)b*L_TOT)*256 + c];
        xx[((long)b*L_TOT)*256 + c] = v;
        return;
    }
    const int t  = (q-1) >> 10;
    const int p  = (q-1) & 1023;
    const int h  = p >> 6;
    const int a  = (p >> 5) & 1;
    const int w  = (p >> 1) & 15;
    const int bb = p & 1;
    const long tok = (long)b*1024 + t*256 + h*16 + w;
    float v = e_buf[tok*1024 + a*512 + bb*256 + c];

    float s = v, s2 = v*v;
    #pragma unroll
    for (int o = 32; o > 0; o >>= 1) { s += __shfl_xor(s, o); s2 += __shfl_xor(s2, o); }
    __shared__ float ps[4], ps2[4];
    __shared__ float mu_s, rs_s;
    const int wv = threadIdx.x >> 6;
    if ((threadIdx.x & 63) == 0) { ps[wv] = s; ps2[wv] = s2; }
    __syncthreads();
    if (threadIdx.x == 0) {
        float S = ps[0]+ps[1]+ps[2]+ps[3];
        float S2 = ps2[0]+ps2[1]+ps2[2]+ps2[3];
        float mu = S * (1.f/256.f);
        float var = S2 * (1.f/256.f) - mu*mu;
        mu_s = mu; rs_s = rsqrtf(var + 1e-5f);
    }
    __syncthreads();
    float outv = (v - mu_s)*rs_s*ln_g[c] + ln_b[c] + skip[((long)b*L_TOT + q)*256 + c];
    xx[((long)b*L_TOT + q)*256 + c] = outv;
}

// ---------------------------------------------------------------------------
// Depthwise causal conv (k=4) + SiLU.  xz: [ROWS,1024] (first 512 = xi)
// ---------------------------------------------------------------------------
__global__ __launch_bounds__(256) void conv_silu(
    const float* __restrict__ xz, const float* __restrict__ cw,
    const float* __restrict__ cb, float* __restrict__ xi)
{
    long idx = (long)blockIdx.x*256 + threadIdx.x;
    if (idx >= (long)ROWS*512) return;
    int d = (int)(idx & 511);
    long rl = idx >> 9;                  // b*L + l
    int l = (int)(rl % L_TOT);
    float acc = cb[d];
    #pragma unroll
    for (int k = 0; k < 4; k++) {
        int ls = l + k - 3;
        if (ls >= 0) acc += cw[d*4 + k] * xz[(rl + (k-3))*1024 + d];
    }
    xi[rl*512 + d] = siluf_(acc);
}

// ---------------------------------------------------------------------------
// xproj (48 dots over 512) + delta = softplus(dt @ Wdt^T + bdt); store B,C
// One block per row.
// ---------------------------------------------------------------------------
__global__ __launch_bounds__(256) void xproj_delta(
    const float* __restrict__ xi, const float* __restrict__ Wx,
    const float* __restrict__ Wdt, const float* __restrict__ bdt,
    float* __restrict__ delta, float* __restrict__ BC)
{
    const int row = blockIdx.x;          // 0..8193
    const int tid = threadIdx.x;
    __shared__ float xr[512];
    __shared__ float dbc[48];
    xr[tid]       = xi[(long)row*512 + tid];
    xr[tid + 256] = xi[(long)row*512 + 256 + tid];
    __syncthreads();
    const int wv = tid >> 6, lane = tid & 63;
    for (int j = wv; j < 48; j += 4) {
        float s = 0.f;
        #pragma unroll
        for (int i = 0; i < 8; i++) {
            int ee = i*64 + lane;
            s += xr[ee] * Wx[j*512 + ee];
        }
        #pragma unroll
        for (int o = 32; o > 0; o >>= 1) s += __shfl_xor(s, o);
        if (lane == 0) dbc[j] = s;
    }
    __syncthreads();
    #pragma unroll
    for (int rep = 0; rep < 2; rep++) {
        int d = rep*256 + tid;
        float s = bdt[d];
        #pragma unroll
        for (int r = 0; r < 16; r++) s += dbc[r]*Wdt[d*16 + r];
        float dl = (s > 20.f) ? s : log1pf(__expf(s));
        delta[(long)row*512 + d] = dl;
    }
    if (tid < 32) BC[(long)row*32 + tid] = dbc[16 + tid];
}

// ---------------------------------------------------------------------------
// Segmented selective scan.  Thread owns (b,d) with 16 states in registers.
// ---------------------------------------------------------------------------
__global__ __launch_bounds__(256) void scan_p1(
    const float* __restrict__ delta, const float* __restrict__ xi,
    const float* __restrict__ BC, const float* __restrict__ A_log,
    float* __restrict__ segH, float* __restrict__ segP)
{
    const int blk = blockIdx.x;          // NSEG*4
    const int seg = blk >> 2;
    const int sub = blk & 3;
    const int b = sub >> 1;
    const int d = (sub & 1)*256 + threadIdx.x;
    float Ar[16];
    #pragma unroll
    for (int n = 0; n < 16; n++) Ar[n] = -__expf(A_log[d*16 + n]);
    float h[16] = {};
    float P[16];
    #pragma unroll
    for (int n = 0; n < 16; n++) P[n] = 1.f;
    const int l0 = seg*SEGLEN;
    const int l1 = min(l0 + SEGLEN, L_TOT);
    for (int l = l0; l < l1; l++) {
        long base = (long)b*L_TOT + l;
        float dl = delta[base*512 + d];
        float xv = xi[base*512 + d];
        const float4* bc = (const float4*)(BC + base*32);
        float4 B0 = bc[0], B1 = bc[1], B2 = bc[2], B3 = bc[3];
        float Bv[16] = {B0.x,B0.y,B0.z,B0.w, B1.x,B1.y,B1.z,B1.w,
                        B2.x,B2.y,B2.z,B2.w, B3.x,B3.y,B3.z,B3.w};
        float dx = dl * xv;
        #pragma unroll
        for (int n = 0; n < 16; n++) {
            float E = __expf(dl * Ar[n]);
            h[n] = h[n]*E + dx*Bv[n];
            P[n] *= E;
        }
    }
    long off = ((long)(seg*2 + b)*512 + d)*16;
    #pragma unroll
    for (int n = 0; n < 4; n++) {
        *(float4*)&segH[off + n*4] = make_float4(h[n*4],h[n*4+1],h[n*4+2],h[n*4+3]);
        *(float4*)&segP[off + n*4] = make_float4(P[n*4],P[n*4+1],P[n*4+2],P[n*4+3]);
    }
}

__global__ __launch_bounds__(256) void scan_p2(
    float* __restrict__ segH, const float* __restrict__ segP)
{
    const int idx = blockIdx.x*256 + threadIdx.x;   // 16384 = (b*512+d)*16+n
    float carry = 0.f;
    for (int s = 0; s < NSEG; s++) {
        long o = (long)s*16384 + idx;
        float hseg = segH[o];
        float p = segP[o];
        segH[o] = carry;               // becomes segment-start state
        carry = p*carry + hseg;
    }
}

__global__ __launch_bounds__(256) void scan_p3(
    const float* __restrict__ delta, float* __restrict__ xiy,
    const float* __restrict__ BC, const float* __restrict__ A_log,
    const float* __restrict__ segH, const float* __restrict__ Dp,
    const float* __restrict__ xz)
{
    const int blk = blockIdx.x;
    const int seg = blk >> 2;
    const int sub = blk & 3;
    const int b = sub >> 1;
    const int d = (sub & 1)*256 + threadIdx.x;
    float Ar[16];
    #pragma unroll
    for (int n = 0; n < 16; n++) Ar[n] = -__expf(A_log[d*16 + n]);
    float h[16];
    long off = ((long)(seg*2 + b)*512 + d)*16;
    #pragma unroll
    for (int n = 0; n < 16; n++) h[n] = segH[off + n];
    const float Dd = Dp[d];
    const int l0 = seg*SEGLEN;
    const int l1 = min(l0 + SEGLEN, L_TOT);
    for (int l = l0; l < l1; l++) {
        long base = (long)b*L_TOT + l;
        float dl = delta[base*512 + d];
        float xv = xiy[base*512 + d];
        const float4* bc = (const float4*)(BC + base*32);
        float4 B0 = bc[0], B1 = bc[1], B2 = bc[2], B3 = bc[3];
        float4 C0 = bc[4], C1 = bc[5], C2 = bc[6], C3 = bc[7];
        float Bv[16] = {B0.x,B0.y,B0.z,B0.w, B1.x,B1.y,B1.z,B1.w,
                        B2.x,B2.y,B2.z,B2.w, B3.x,B3.y,B3.z,B3.w};
        float Cv[16] = {C0.x,C0.y,C0.z,C0.w, C1.x,C1.y,C1.z,C1.w,
                        C2.x,C2.y,C2.z,C2.w, C3.x,C3.y,C3.z,C3.w};
        float dx = dl * xv;
        float y = 0.f;
        #pragma unroll
        for (int n = 0; n < 16; n++) {
            float E = __expf(dl * Ar[n]);
            h[n] = h[n]*E + dx*Bv[n];
            y += h[n]*Cv[n];
        }
        float z = xz[base*1024 + 512 + d];
        float yo = (y + xv*Dd) * siluf_(z);
        xiy[base*512 + d] = yo;        // in-place over xi (read-before-write)
    }
}

// ---------------------------------------------------------------------------
// BatchNorm over axes (0,1): 8194 rows x 256 channels
// ---------------------------------------------------------------------------
__global__ void zero_stats(float* __restrict__ stats) { stats[threadIdx.x] = 0.f; }

__global__ __launch_bounds__(256) void bn_reduce(
    const float* __restrict__ xx, float* __restrict__ stats)
{
    const int c = threadIdx.x;
    float s = 0.f, s2 = 0.f;
    for (int r = blockIdx.x; r < ROWS; r += gridDim.x) {
        float v = xx[(long)r*256 + c];
        s += v; s2 += v*v;
    }
    atomicAdd(&stats[c], s);
    atomicAdd(&stats[256 + c], s2);
}

__global__ __launch_bounds__(256) void bn_apply(
    const float* __restrict__ xx, const float* __restrict__ stats,
    const float* __restrict__ g, const float* __restrict__ bta,
    float* __restrict__ out)
{
    long idx = (long)blockIdx.x*256 + threadIdx.x;
    if (idx == 0) out[(long)ROWS*256] = 1024.0f;   // second output: 4*N
    if (idx >= (long)ROWS*256) return;
    int c = (int)(idx & 255);
    float mu = stats[c] * (1.f/ROWS);
    float var = stats[256 + c] * (1.f/ROWS) - mu*mu;
    out[idx] = (xx[idx] - mu)*rsqrtf(var + 1e-5f)*g[c] + bta[c];
}

// ---------------------------------------------------------------------------
extern "C" void kernel_launch(void* const* d_in, const int* in_sizes, int n_in,
                              void* d_out, int out_size, void* d_ws, size_t ws_size,
                              hipStream_t stream)
{
    const float* x        = (const float*)d_in[0];
    const float* skip     = (const float*)d_in[1];
    const float* exp_w    = (const float*)d_in[2];
    const float* ln_g     = (const float*)d_in[3];
    const float* ln_b     = (const float*)d_in[4];
    const float* cls_w    = (const float*)d_in[5];
    const float* cls_b    = (const float*)d_in[6];
    const float* in_proj_w= (const float*)d_in[7];
    const float* conv_w   = (const float*)d_in[8];
    const float* conv_b   = (const float*)d_in[9];
    const float* xproj_w  = (const float*)d_in[10];
    const float* dt_w     = (const float*)d_in[11];
    const float* dt_b     = (const float*)d_in[12];
    const float* A_log    = (const float*)d_in[13];
    const float* Dp       = (const float*)d_in[14];
    const float* out_w    = (const float*)d_in[15];
    const float* bn_g     = (const float*)d_in[16];
    const float* bn_b     = (const float*)d_in[17];

    float* ws = (float*)d_ws;
    float* xx    = ws;                       // 2,097,664
    float* xz    = xx + 2097664;             // 8,390,656
    float* e_buf = xz;                       // alias (used only before layer 0)
    float* xi    = xz + 8390656;             // 4,195,328
    float* dbuf  = xi + 4195328;             // 4,195,328
    float* BC    = dbuf + 4195328;           // 262,208
    float* segH  = BC + 262208;              // 1,048,576
    float* segP  = segH + 1048576;           // 1,048,576
    float* stats = segP + 1048576;           // 512
    float* out   = (float*)d_out;

    // 1) expand: e[2048,1024] = toks @ exp_w^T
    gemm_f32<1><<<dim3(1024/64, 2048/64), 256, 0, stream>>>(x, exp_w, e_buf, 2048, 1024, 512);
    // 2) rearrange + LN + cls + skip -> xx
    rearrange_ln_cls<<<ROWS, 256, 0, stream>>>(e_buf, x, cls_w, cls_b, ln_g, ln_b, skip, xx);

    for (int layer = 0; layer < 2; layer++) {
        // in_proj: xz[ROWS,1024] = xx @ Wi^T
        gemm_f32<0><<<dim3(1024/64, (ROWS+63)/64), 256, 0, stream>>>(
            xx, in_proj_w + layer*1024*256, xz, ROWS, 1024, 256);
        conv_silu<<<((long)ROWS*512 + 255)/256, 256, 0, stream>>>(
            xz, conv_w + layer*512*4, conv_b + layer*512, xi);
        xproj_delta<<<ROWS, 256, 0, stream>>>(
            xi, xproj_w + layer*48*512, dt_w + layer*512*16, dt_b + layer*512, dbuf, BC);
        scan_p1<<<NSEG*4, 256, 0, stream>>>(dbuf, xi, BC, A_log + layer*512*16, segH, segP);
        scan_p2<<<64, 256, 0, stream>>>(segH, segP);
        scan_p3<<<NSEG*4, 256, 0, stream>>>(dbuf, xi, BC, A_log + layer*512*16, segH,
                                            Dp + layer*512, xz);
        // out_proj: xx[ROWS,256] = y @ Wo^T   (y lives in xi, in-place from p3)
        gemm_f32<0><<<dim3(256/64, (ROWS+63)/64), 256, 0, stream>>>(
            xi, out_w + layer*256*512, xx, ROWS, 256, 512);
    }

    zero_stats<<<1, 512, 0, stream>>>(stats);
    bn_reduce<<<128, 256, 0, stream>>>(xx, stats);
    bn_apply<<<((long)ROWS*256 + 255)/256 + 1, 256, 0, stream>>>(xx, stats, bn_g, bn_b, out);
}

// Round 2
// 537.540 us; speedup vs baseline: 1.4345x; 1.4345x over previous
//
#include <hip/hip_runtime.h>
#include <hip/hip_bf16.h>
#include <math.h>

#define L_TOT 4097
#define BSZ 2
#define ROWS (BSZ*L_TOT)   // 8194
#define NSEG 64
#define SEGLEN 65          // 64*65 = 4160 >= 4097

typedef __bf16 bf16x8 __attribute__((ext_vector_type(8)));
typedef float  f32x4  __attribute__((ext_vector_type(4)));
#define ASTR 56            // LDS row stride (bf16 elems): 112B, 16B-aligned, 2-way banks

__device__ __forceinline__ float sigmoidf_(float v){ return 1.0f/(1.0f+__expf(-v)); }
__device__ __forceinline__ float siluf_(float v){ return v * sigmoidf_(v); }

// ---------------------------------------------------------------------------
// f32 -> bf16 converters
// ---------------------------------------------------------------------------
__global__ __launch_bounds__(256) void cvt_f32_bf16(
    const float* __restrict__ in, __bf16* __restrict__ out, long n)
{
    long i = ((long)blockIdx.x*256 + threadIdx.x)*8;
    if (i >= n) return;
    float4 a = *(const float4*)(in+i), b = *(const float4*)(in+i+4);
    bf16x8 o;
    o[0]=(__bf16)a.x; o[1]=(__bf16)a.y; o[2]=(__bf16)a.z; o[3]=(__bf16)a.w;
    o[4]=(__bf16)b.x; o[5]=(__bf16)b.y; o[6]=(__bf16)b.z; o[7]=(__bf16)b.w;
    *(bf16x8*)(out+i) = o;
}

__global__ __launch_bounds__(256) void cvt_gather_x(
    const float* __restrict__ x, __bf16* __restrict__ out)
{
    long i = ((long)blockIdx.x*256 + threadIdx.x)*8;
    if (i >= 2048L*512) return;
    int row = (int)(i >> 9), col = (int)(i & 511);
    long srow = row + (row >> 10) + 1;           // skip cls token per batch
    const float* src = x + srow*512 + col;
    float4 a = *(const float4*)src, b = *(const float4*)(src+4);
    bf16x8 o;
    o[0]=(__bf16)a.x; o[1]=(__bf16)a.y; o[2]=(__bf16)a.z; o[3]=(__bf16)a.w;
    o[4]=(__bf16)b.x; o[5]=(__bf16)b.y; o[6]=(__bf16)b.z; o[7]=(__bf16)b.w;
    *(bf16x8*)(out+i) = o;
}

// ---------------------------------------------------------------------------
// bf16 MFMA GEMM: C[M,N] = A[M,K] * W[N,K]^T, f32 accumulate.
// BM=128, BN=64, BK=32, 256 threads (4 waves, each wave: 32 rows x 64 cols).
// DUAL: also store bf16 copy of C.
// ---------------------------------------------------------------------------
template<bool DUAL>
__global__ __launch_bounds__(256) void gemm_bf16(
    const __bf16* __restrict__ A, const __bf16* __restrict__ W,
    float* __restrict__ C, __bf16* __restrict__ C2, int M, int N, int K)
{
    __shared__ __bf16 Als[128*ASTR];
    __shared__ __bf16 Wls[64*ASTR];
    const int tid = threadIdx.x;
    const int lane = tid & 63, w = tid >> 6;
    const int n0 = blockIdx.x*64, m0 = blockIdx.y*128;

    f32x4 zero = {0.f,0.f,0.f,0.f};
    f32x4 acc[2][4];
    #pragma unroll
    for (int i=0;i<2;i++)
        #pragma unroll
        for (int j=0;j<4;j++) acc[i][j] = zero;

    const int arow = tid >> 1, ahalf = tid & 1;   // A staging: 2 thr/row, 32B each
    const int wrow = tid >> 2, wseg = tid & 3;    // W staging: 4 thr/row, 16B each
    const int fr = lane & 15, fc = lane >> 4;

    for (int k0 = 0; k0 < K; k0 += 32) {
        bf16x8 av0 = {}, av1 = {};
        if (m0 + arow < M) {
            const __bf16* src = A + (long)(m0+arow)*K + k0 + ahalf*16;
            av0 = *(const bf16x8*)src;
            av1 = *(const bf16x8*)(src+8);
        }
        bf16x8 wv = *(const bf16x8*)(W + (long)(n0+wrow)*K + k0 + wseg*8);
        __syncthreads();
        *(bf16x8*)&Als[arow*ASTR + ahalf*16]     = av0;
        *(bf16x8*)&Als[arow*ASTR + ahalf*16 + 8] = av1;
        *(bf16x8*)&Wls[wrow*ASTR + wseg*8]       = wv;
        __syncthreads();

        bf16x8 a0 = *(const bf16x8*)&Als[(w*32 +      fr)*ASTR + fc*8];
        bf16x8 a1 = *(const bf16x8*)&Als[(w*32 + 16 + fr)*ASTR + fc*8];
        #pragma unroll
        for (int j = 0; j < 4; j++) {
            bf16x8 bv = *(const bf16x8*)&Wls[(j*16 + fr)*ASTR + fc*8];
            acc[0][j] = __builtin_amdgcn_mfma_f32_16x16x32_bf16(a0, bv, acc[0][j], 0,0,0);
            acc[1][j] = __builtin_amdgcn_mfma_f32_16x16x32_bf16(a1, bv, acc[1][j], 0,0,0);
        }
    }
    // D layout: col = lane&15, row = (lane>>4)*4 + reg
    #pragma unroll
    for (int i = 0; i < 2; i++) {
        #pragma unroll
        for (int rr = 0; rr < 4; rr++) {
            int grow = m0 + w*32 + i*16 + fc*4 + rr;
            if (grow < M) {
                #pragma unroll
                for (int j = 0; j < 4; j++) {
                    float v = acc[i][j][rr];
                    long o = (long)grow*N + n0 + j*16 + fr;
                    C[o] = v;
                    if (DUAL) C2[o] = (__bf16)v;
                }
            }
        }
    }
}

// ---------------------------------------------------------------------------
// Patch rearrange + LayerNorm(256) + skip add (+ bf16 dual store); cls row q==0
// ---------------------------------------------------------------------------
__global__ __launch_bounds__(256) void rearrange_ln_cls(
    const float* __restrict__ e_buf, const float* __restrict__ x,
    const float* __restrict__ cls_w, const float* __restrict__ cls_b,
    const float* __restrict__ ln_g, const float* __restrict__ ln_b,
    const float* __restrict__ skip, float* __restrict__ xx,
    __bf16* __restrict__ xxb)
{
    const int blk = blockIdx.x;
    const int b = blk / L_TOT;
    const int q = blk % L_TOT;
    const int c = threadIdx.x;

    if (q == 0) {
        __shared__ float xr[512];
        const float* xrow = x + (long)b*1025*512;
        xr[c] = xrow[c]; xr[c+256] = xrow[c+256];
        __syncthreads();
        float acc = cls_b[c];
        const float4* wrow = (const float4*)(cls_w + (long)c*512);
        #pragma unroll 8
        for (int m4 = 0; m4 < 128; m4++) {
            float4 wv = wrow[m4];
            float4 xv = *(const float4*)&xr[m4*4];
            acc += wv.x*xv.x + wv.y*xv.y + wv.z*xv.z + wv.w*xv.w;
        }
        long o = (long)b*L_TOT*256 + c;
        float v = acc + skip[o];
        xx[o] = v; xxb[o] = (__bf16)v;
        return;
    }
    const int t  = (q-1) >> 10;
    const int p  = (q-1) & 1023;
    const int h  = p >> 6;
    const int a  = (p >> 5) & 1;
    const int w  = (p >> 1) & 15;
    const int bb = p & 1;
    const long tok = (long)b*1024 + t*256 + h*16 + w;
    float v = e_buf[tok*1024 + a*512 + bb*256 + c];

    float s = v, s2 = v*v;
    #pragma unroll
    for (int o = 32; o > 0; o >>= 1) { s += __shfl_xor(s, o); s2 += __shfl_xor(s2, o); }
    __shared__ float ps[4], ps2[4];
    __shared__ float mu_s, rs_s;
    const int wv = threadIdx.x >> 6;
    if ((threadIdx.x & 63) == 0) { ps[wv] = s; ps2[wv] = s2; }
    __syncthreads();
    if (threadIdx.x == 0) {
        float S = ps[0]+ps[1]+ps[2]+ps[3];
        float S2 = ps2[0]+ps2[1]+ps2[2]+ps2[3];
        float mu = S * (1.f/256.f);
        float var = S2 * (1.f/256.f) - mu*mu;
        mu_s = mu; rs_s = rsqrtf(var + 1e-5f);
    }
    __syncthreads();
    long o = ((long)b*L_TOT + q)*256 + c;
    float outv = (v - mu_s)*rs_s*ln_g[c] + ln_b[c] + skip[o];
    xx[o] = outv; xxb[o] = (__bf16)outv;
}

// ---------------------------------------------------------------------------
// Depthwise causal conv (k=4) + SiLU
// ---------------------------------------------------------------------------
__global__ __launch_bounds__(256) void conv_silu(
    const float* __restrict__ xz, const float* __restrict__ cw,
    const float* __restrict__ cb, float* __restrict__ xi)
{
    long idx = (long)blockIdx.x*256 + threadIdx.x;
    if (idx >= (long)ROWS*512) return;
    int d = (int)(idx & 511);
    long rl = idx >> 9;
    int l = (int)(rl % L_TOT);
    float acc = cb[d];
    #pragma unroll
    for (int k = 0; k < 4; k++) {
        int ls = l + k - 3;
        if (ls >= 0) acc += cw[d*4 + k] * xz[(rl + (k-3))*1024 + d];
    }
    xi[rl*512 + d] = siluf_(acc);
}

// ---------------------------------------------------------------------------
// xproj + delta softplus
// ---------------------------------------------------------------------------
__global__ __launch_bounds__(256) void xproj_delta(
    const float* __restrict__ xi, const float* __restrict__ Wx,
    const float* __restrict__ Wdt, const float* __restrict__ bdt,
    float* __restrict__ delta, float* __restrict__ BC)
{
    const int row = blockIdx.x;
    const int tid = threadIdx.x;
    __shared__ float xr[512];
    __shared__ float dbc[48];
    xr[tid]       = xi[(long)row*512 + tid];
    xr[tid + 256] = xi[(long)row*512 + 256 + tid];
    __syncthreads();
    const int wv = tid >> 6, lane = tid & 63;
    for (int j = wv; j < 48; j += 4) {
        float s = 0.f;
        #pragma unroll
        for (int i = 0; i < 8; i++) {
            int ee = i*64 + lane;
            s += xr[ee] * Wx[j*512 + ee];
        }
        #pragma unroll
        for (int o = 32; o > 0; o >>= 1) s += __shfl_xor(s, o);
        if (lane == 0) dbc[j] = s;
    }
    __syncthreads();
    #pragma unroll
    for (int rep = 0; rep < 2; rep++) {
        int d = rep*256 + tid;
        float s = bdt[d];
        #pragma unroll
        for (int r = 0; r < 16; r++) s += dbc[r]*Wdt[d*16 + r];
        float dl = (s > 20.f) ? s : log1pf(__expf(s));
        delta[(long)row*512 + d] = dl;
    }
    if (tid < 32) BC[(long)row*32 + tid] = dbc[16 + tid];
}

// ---------------------------------------------------------------------------
// Segmented scan: 4 threads per (b,d), 4 states each
// ---------------------------------------------------------------------------
__global__ __launch_bounds__(256) void scan_p1(
    const float* __restrict__ delta, const float* __restrict__ xi,
    const float* __restrict__ BC, const float* __restrict__ A_log,
    float* __restrict__ segH, float* __restrict__ segP)
{
    const int seg = blockIdx.x >> 4;
    const int t = ((blockIdx.x & 15) << 8) + threadIdx.x;  // 0..4095
    const int b = t >> 11;
    const int d = (t >> 2) & 511;
    const int ng = t & 3;
    float4 Al = *(const float4*)(A_log + d*16 + ng*4);
    float Ar[4] = {-__expf(Al.x), -__expf(Al.y), -__expf(Al.z), -__expf(Al.w)};
    float h[4] = {0,0,0,0};
    float P[4] = {1,1,1,1};
    const int l0 = seg*SEGLEN;
    const int l1 = min(l0 + SEGLEN, L_TOT);
    for (int l = l0; l < l1; l++) {
        long base = (long)b*L_TOT + l;
        float dl = delta[base*512 + d];
        float xv = xi[base*512 + d];
        float4 Bv = *(const float4*)(BC + base*32 + ng*4);
        float dx = dl*xv;
        float B4[4] = {Bv.x, Bv.y, Bv.z, Bv.w};
        #pragma unroll
        for (int n = 0; n < 4; n++) {
            float E = __expf(dl*Ar[n]);
            h[n] = h[n]*E + dx*B4[n];
            P[n] *= E;
        }
    }
    long off = ((long)(seg*2 + b)*512 + d)*16 + ng*4;
    *(float4*)&segH[off] = make_float4(h[0],h[1],h[2],h[3]);
    *(float4*)&segP[off] = make_float4(P[0],P[1],P[2],P[3]);
}

__global__ __launch_bounds__(256) void scan_p2(
    float* __restrict__ segH, const float* __restrict__ segP)
{
    const int idx = blockIdx.x*256 + threadIdx.x;   // 16384
    float carry = 0.f;
    for (int s0 = 0; s0 < NSEG; s0 += 8) {
        float hh[8], pp[8];
        #pragma unroll
        for (int j = 0; j < 8; j++) {
            long o = (long)(s0+j)*16384 + idx;
            hh[j] = segH[o]; pp[j] = segP[o];
        }
        #pragma unroll
        for (int j = 0; j < 8; j++) {
            long o = (long)(s0+j)*16384 + idx;
            segH[o] = carry;
            carry = pp[j]*carry + hh[j];
        }
    }
}

__global__ __launch_bounds__(256) void scan_p3(
    const float* __restrict__ delta, const float* __restrict__ xi,
    const float* __restrict__ BC, const float* __restrict__ A_log,
    const float* __restrict__ segH, const float* __restrict__ Dp,
    const float* __restrict__ xz, __bf16* __restrict__ yb)
{
    const int seg = blockIdx.x >> 4;
    const int t = ((blockIdx.x & 15) << 8) + threadIdx.x;
    const int b = t >> 11;
    const int d = (t >> 2) & 511;
    const int ng = t & 3;
    float4 Al = *(const float4*)(A_log + d*16 + ng*4);
    float Ar[4] = {-__expf(Al.x), -__expf(Al.y), -__expf(Al.z), -__expf(Al.w)};
    long off = ((long)(seg*2 + b)*512 + d)*16 + ng*4;
    float4 h4 = *(const float4*)&segH[off];
    float h[4] = {h4.x, h4.y, h4.z, h4.w};
    const float Dd = Dp[d];
    const int l0 = seg*SEGLEN;
    const int l1 = min(l0 + SEGLEN, L_TOT);
    for (int l = l0; l < l1; l++) {
        long base = (long)b*L_TOT + l;
        float dl = delta[base*512 + d];
        float xv = xi[base*512 + d];
        float4 Bv = *(const float4*)(BC + base*32 + ng*4);
        float4 Cv = *(const float4*)(BC + base*32 + 16 + ng*4);
        float dx = dl*xv;
        float B4[4] = {Bv.x, Bv.y, Bv.z, Bv.w};
        float C4[4] = {Cv.x, Cv.y, Cv.z, Cv.w};
        float y = 0.f;
        #pragma unroll
        for (int n = 0; n < 4; n++) {
            float E = __expf(dl*Ar[n]);
            h[n] = h[n]*E + dx*B4[n];
            y += h[n]*C4[n];
        }
        y += __shfl_xor(y, 1);
        y += __shfl_xor(y, 2);
        if (ng == 0) {
            float z = xz[base*1024 + 512 + d];
            float yo = (y + xv*Dd) * siluf_(z);
            yb[base*512 + d] = (__bf16)yo;
        }
    }
}

// ---------------------------------------------------------------------------
// BatchNorm over rows
// ---------------------------------------------------------------------------
__global__ void zero_stats(float* __restrict__ stats) { stats[threadIdx.x] = 0.f; }

__global__ __launch_bounds__(256) void bn_reduce(
    const float* __restrict__ xx, float* __restrict__ stats)
{
    const int c = threadIdx.x;
    float s = 0.f, s2 = 0.f;
    for (int r = blockIdx.x; r < ROWS; r += gridDim.x) {
        float v = xx[(long)r*256 + c];
        s += v; s2 += v*v;
    }
    atomicAdd(&stats[c], s);
    atomicAdd(&stats[256 + c], s2);
}

__global__ __launch_bounds__(256) void bn_apply(
    const float* __restrict__ xx, const float* __restrict__ stats,
    const float* __restrict__ g, const float* __restrict__ bta,
    float* __restrict__ out)
{
    long idx = (long)blockIdx.x*256 + threadIdx.x;
    if (idx == 0) out[(long)ROWS*256] = 1024.0f;
    if (idx >= (long)ROWS*256) return;
    int c = (int)(idx & 255);
    float mu = stats[c] * (1.f/ROWS);
    float var = stats[256 + c] * (1.f/ROWS) - mu*mu;
    out[idx] = (xx[idx] - mu)*rsqrtf(var + 1e-5f)*g[c] + bta[c];
}

// ---------------------------------------------------------------------------
extern "C" void kernel_launch(void* const* d_in, const int* in_sizes, int n_in,
                              void* d_out, int out_size, void* d_ws, size_t ws_size,
                              hipStream_t stream)
{
    const float* x        = (const float*)d_in[0];
    const float* skip     = (const float*)d_in[1];
    const float* exp_w    = (const float*)d_in[2];
    const float* ln_g     = (const float*)d_in[3];
    const float* ln_b     = (const float*)d_in[4];
    const float* cls_w    = (const float*)d_in[5];
    const float* cls_b    = (const float*)d_in[6];
    const float* in_proj_w= (const float*)d_in[7];
    const float* conv_w   = (const float*)d_in[8];
    const float* conv_b   = (const float*)d_in[9];
    const float* xproj_w  = (const float*)d_in[10];
    const float* dt_w     = (const float*)d_in[11];
    const float* dt_b     = (const float*)d_in[12];
    const float* A_log    = (const float*)d_in[13];
    const float* Dp       = (const float*)d_in[14];
    const float* out_w    = (const float*)d_in[15];
    const float* bn_g     = (const float*)d_in[16];
    const float* bn_b     = (const float*)d_in[17];

    float* ws = (float*)d_ws;
    float* xx    = ws;                       // 2,097,664
    float* xz    = xx + 2097664;             // 8,390,656
    float* e_buf = xz;                       // alias (pre-layer only)
    float* xi    = xz + 8390656;             // 4,195,328
    float* dbuf  = xi + 4195328;             // 4,195,328
    float* BC    = dbuf + 4195328;           // 262,208
    float* segH  = BC + 262208;              // 1,048,576
    float* segP  = segH + 1048576;           // 1,048,576
    float* stats = segP + 1048576;           // 512
    __bf16* Wb   = (__bf16*)(stats + 512);   // 1,310,720 bf16
    __bf16* expWb = Wb;
    __bf16* inWb  = Wb + 524288;             // 2 layers x 262144
    __bf16* outWb = Wb + 1048576;            // 2 layers x 131072
    __bf16* xxb  = (__bf16*)((float*)(Wb + 1310720));      // 2,097,664 bf16
    __bf16* yb   = xxb + 2097664;            // 4,195,328 bf16 (also Axb alias)
    __bf16* Axb  = yb;                       // 1,048,576 bf16 (pre-layer only)
    float* out   = (float*)d_out;

    // weight + input conversion
    cvt_f32_bf16<<<(524288/8+255)/256, 256, 0, stream>>>(exp_w, expWb, 524288);
    cvt_f32_bf16<<<(524288/8+255)/256, 256, 0, stream>>>(in_proj_w, inWb, 524288);
    cvt_f32_bf16<<<(262144/8+255)/256, 256, 0, stream>>>(out_w, outWb, 262144);
    cvt_gather_x<<<(1048576/8)/256, 256, 0, stream>>>(x, Axb);

    // expand: e[2048,1024] = Axb @ expWb^T
    gemm_bf16<false><<<dim3(1024/64, 2048/128), 256, 0, stream>>>(
        Axb, expWb, e_buf, nullptr, 2048, 1024, 512);
    rearrange_ln_cls<<<ROWS, 256, 0, stream>>>(
        e_buf, x, cls_w, cls_b, ln_g, ln_b, skip, xx, xxb);

    for (int layer = 0; layer < 2; layer++) {
        gemm_bf16<false><<<dim3(1024/64, (ROWS+127)/128), 256, 0, stream>>>(
            xxb, inWb + layer*262144, xz, nullptr, ROWS, 1024, 256);
        conv_silu<<<((long)ROWS*512 + 255)/256, 256, 0, stream>>>(
            xz, conv_w + layer*512*4, conv_b + layer*512, xi);
        xproj_delta<<<ROWS, 256, 0, stream>>>(
            xi, xproj_w + layer*48*512, dt_w + layer*512*16, dt_b + layer*512, dbuf, BC);
        scan_p1<<<NSEG*16, 256, 0, stream>>>(
            dbuf, xi, BC, A_log + layer*512*16, segH, segP);
        scan_p2<<<64, 256, 0, stream>>>(segH, segP);
        scan_p3<<<NSEG*16, 256, 0, stream>>>(
            dbuf, xi, BC, A_log + layer*512*16, segH, Dp + layer*512, xz, yb);
        if (layer == 0) {
            gemm_bf16<true><<<dim3(256/64, (ROWS+127)/128), 256, 0, stream>>>(
                yb, outWb, xx, xxb, ROWS, 256, 512);
        } else {
            gemm_bf16<false><<<dim3(256/64, (ROWS+127)/128), 256, 0, stream>>>(
                yb, outWb + 131072, xx, nullptr, ROWS, 256, 512);
        }
    }

    zero_stats<<<1, 512, 0, stream>>>(stats);
    bn_reduce<<<128, 256, 0, stream>>>(xx, stats);
    bn_apply<<<((long)ROWS*256 + 255)/256 + 1, 256, 0, stream>>>(xx, stats, bn_g, bn_b, out);
}

// Round 3
// 479.706 us; speedup vs baseline: 1.6074x; 1.1206x over previous
//
#include <hip/hip_runtime.h>
#include <hip/hip_bf16.h>
#include <math.h>

#define L_TOT 4097
#define BSZ 2
#define ROWS (BSZ*L_TOT)   // 8194
#define NSEG 128
#define SEGLEN 33          // 128*33 = 4224 >= 4097

typedef __bf16 bf16x8 __attribute__((ext_vector_type(8)));
typedef float  f32x4  __attribute__((ext_vector_type(4)));
#define ASTR 56            // LDS row stride (bf16): 112B

__device__ __forceinline__ float sigmoidf_(float v){ return 1.0f/(1.0f+__expf(-v)); }
__device__ __forceinline__ float siluf_(float v){ return v * sigmoidf_(v); }

// ---------------------------------------------------------------------------
// f32 -> bf16 weight conversion (4 tensors in one launch)
// sizes: exp 524288 | in_proj 524288 | out 262144 | xproj 49152
// ---------------------------------------------------------------------------
__global__ __launch_bounds__(256) void cvt4(
    const float* __restrict__ w0, const float* __restrict__ w1,
    const float* __restrict__ w2, const float* __restrict__ w3,
    __bf16* __restrict__ o0, __bf16* __restrict__ o1,
    __bf16* __restrict__ o2, __bf16* __restrict__ o3)
{
    long i = ((long)blockIdx.x*256 + threadIdx.x)*8;
    const float* src; __bf16* dst; long off;
    if (i < 524288)        { src = w0; dst = o0; off = i; }
    else if (i < 1048576)  { src = w1; dst = o1; off = i - 524288; }
    else if (i < 1310720)  { src = w2; dst = o2; off = i - 1048576; }
    else if (i < 1359872)  { src = w3; dst = o3; off = i - 1310720; }
    else return;
    float4 a = *(const float4*)(src+off), b = *(const float4*)(src+off+4);
    bf16x8 o;
    o[0]=(__bf16)a.x; o[1]=(__bf16)a.y; o[2]=(__bf16)a.z; o[3]=(__bf16)a.w;
    o[4]=(__bf16)b.x; o[5]=(__bf16)b.y; o[6]=(__bf16)b.z; o[7]=(__bf16)b.w;
    *(bf16x8*)(dst+off) = o;
}

__global__ __launch_bounds__(256) void cvt_gather_x(
    const float* __restrict__ x, __bf16* __restrict__ out)
{
    long i = ((long)blockIdx.x*256 + threadIdx.x)*8;
    if (i >= 2048L*512) return;
    int row = (int)(i >> 9), col = (int)(i & 511);
    long srow = row + (row >> 10) + 1;           // skip cls token per batch
    const float* src = x + srow*512 + col;
    float4 a = *(const float4*)src, b = *(const float4*)(src+4);
    bf16x8 o;
    o[0]=(__bf16)a.x; o[1]=(__bf16)a.y; o[2]=(__bf16)a.z; o[3]=(__bf16)a.w;
    o[4]=(__bf16)b.x; o[5]=(__bf16)b.y; o[6]=(__bf16)b.z; o[7]=(__bf16)b.w;
    *(bf16x8*)(out+i) = o;
}

// ---------------------------------------------------------------------------
// bf16 MFMA GEMM: C[M,N] = A[M,K] * W[N,K]^T, f32 accumulate.
// BM=128, BN=64, BK=32, 256 threads. SMODE: 0=f32 C, 1=both, 2=bf16 C2 only.
// ---------------------------------------------------------------------------
template<int SMODE>
__global__ __launch_bounds__(256) void gemm_bf16(
    const __bf16* __restrict__ A, const __bf16* __restrict__ W,
    float* __restrict__ C, __bf16* __restrict__ C2, int M, int N, int K)
{
    __shared__ __bf16 Als[128*ASTR];
    __shared__ __bf16 Wls[64*ASTR];
    const int tid = threadIdx.x;
    const int lane = tid & 63, w = tid >> 6;
    const int n0 = blockIdx.x*64, m0 = blockIdx.y*128;

    f32x4 zero = {0.f,0.f,0.f,0.f};
    f32x4 acc[2][4];
    #pragma unroll
    for (int i=0;i<2;i++)
        #pragma unroll
        for (int j=0;j<4;j++) acc[i][j] = zero;

    const int arow = tid >> 1, ahalf = tid & 1;
    const int wrow = tid >> 2, wseg = tid & 3;
    const int fr = lane & 15, fc = lane >> 4;

    for (int k0 = 0; k0 < K; k0 += 32) {
        bf16x8 av0 = {}, av1 = {};
        if (m0 + arow < M) {
            const __bf16* src = A + (long)(m0+arow)*K + k0 + ahalf*16;
            av0 = *(const bf16x8*)src;
            av1 = *(const bf16x8*)(src+8);
        }
        bf16x8 wv = *(const bf16x8*)(W + (long)(n0+wrow)*K + k0 + wseg*8);
        __syncthreads();
        *(bf16x8*)&Als[arow*ASTR + ahalf*16]     = av0;
        *(bf16x8*)&Als[arow*ASTR + ahalf*16 + 8] = av1;
        *(bf16x8*)&Wls[wrow*ASTR + wseg*8]       = wv;
        __syncthreads();

        bf16x8 a0 = *(const bf16x8*)&Als[(w*32 +      fr)*ASTR + fc*8];
        bf16x8 a1 = *(const bf16x8*)&Als[(w*32 + 16 + fr)*ASTR + fc*8];
        #pragma unroll
        for (int j = 0; j < 4; j++) {
            bf16x8 bv = *(const bf16x8*)&Wls[(j*16 + fr)*ASTR + fc*8];
            acc[0][j] = __builtin_amdgcn_mfma_f32_16x16x32_bf16(a0, bv, acc[0][j], 0,0,0);
            acc[1][j] = __builtin_amdgcn_mfma_f32_16x16x32_bf16(a1, bv, acc[1][j], 0,0,0);
        }
    }
    #pragma unroll
    for (int i = 0; i < 2; i++) {
        #pragma unroll
        for (int rr = 0; rr < 4; rr++) {
            int grow = m0 + w*32 + i*16 + fc*4 + rr;
            if (grow < M) {
                #pragma unroll
                for (int j = 0; j < 4; j++) {
                    float v = acc[i][j][rr];
                    long o = (long)grow*N + n0 + j*16 + fr;
                    if (SMODE != 2) C[o] = v;
                    if (SMODE != 0) C2[o] = (__bf16)v;
                }
            }
        }
    }
}

// ---------------------------------------------------------------------------
// dbc GEMM: dbc[M,48] = xib[M,512] @ Wx[48,512]^T.  BM=64, 128 threads
// ---------------------------------------------------------------------------
__global__ __launch_bounds__(128) void gemm_dbc(
    const __bf16* __restrict__ A, const __bf16* __restrict__ W,
    float* __restrict__ C, int M)
{
    __shared__ __bf16 Als[64*ASTR];
    __shared__ __bf16 Wls[48*ASTR];
    const int tid = threadIdx.x;
    const int lane = tid & 63, w = tid >> 6;
    const int m0 = blockIdx.x*64;
    f32x4 zero = {0.f,0.f,0.f,0.f};
    f32x4 acc[2][3];
    #pragma unroll
    for (int i=0;i<2;i++)
        #pragma unroll
        for (int j=0;j<3;j++) acc[i][j] = zero;

    const int arow = tid >> 1, ahalf = tid & 1;
    const int fr = lane & 15, fc = lane >> 4;

    for (int k0 = 0; k0 < 512; k0 += 32) {
        bf16x8 av0 = {}, av1 = {};
        if (m0 + arow < M) {
            const __bf16* src = A + (long)(m0+arow)*512 + k0 + ahalf*16;
            av0 = *(const bf16x8*)src;
            av1 = *(const bf16x8*)(src+8);
        }
        bf16x8 wv0 = {}, wv1 = {};
        if (tid < 96) {
            const __bf16* src = W + (long)(tid>>1)*512 + k0 + (tid&1)*16;
            wv0 = *(const bf16x8*)src;
            wv1 = *(const bf16x8*)(src+8);
        }
        __syncthreads();
        *(bf16x8*)&Als[arow*ASTR + ahalf*16]     = av0;
        *(bf16x8*)&Als[arow*ASTR + ahalf*16 + 8] = av1;
        if (tid < 96) {
            *(bf16x8*)&Wls[(tid>>1)*ASTR + (tid&1)*16]     = wv0;
            *(bf16x8*)&Wls[(tid>>1)*ASTR + (tid&1)*16 + 8] = wv1;
        }
        __syncthreads();

        bf16x8 a0 = *(const bf16x8*)&Als[(w*32 +      fr)*ASTR + fc*8];
        bf16x8 a1 = *(const bf16x8*)&Als[(w*32 + 16 + fr)*ASTR + fc*8];
        #pragma unroll
        for (int j = 0; j < 3; j++) {
            bf16x8 bv = *(const bf16x8*)&Wls[(j*16 + fr)*ASTR + fc*8];
            acc[0][j] = __builtin_amdgcn_mfma_f32_16x16x32_bf16(a0, bv, acc[0][j], 0,0,0);
            acc[1][j] = __builtin_amdgcn_mfma_f32_16x16x32_bf16(a1, bv, acc[1][j], 0,0,0);
        }
    }
    #pragma unroll
    for (int i = 0; i < 2; i++) {
        #pragma unroll
        for (int rr = 0; rr < 4; rr++) {
            int grow = m0 + w*32 + i*16 + fc*4 + rr;
            if (grow < M) {
                #pragma unroll
                for (int j = 0; j < 3; j++)
                    C[(long)grow*48 + j*16 + fr] = acc[i][j][rr];
            }
        }
    }
}

// ---------------------------------------------------------------------------
// delta: softplus(dbc[:, :16] @ Wdt[512,16]^T + bdt) -> bf16 [ROWS,512]
// ---------------------------------------------------------------------------
__global__ __launch_bounds__(256) void delta_k(
    const float* __restrict__ dbc, const float* __restrict__ Wdt,
    const float* __restrict__ bdt, __bf16* __restrict__ deltab)
{
    const int d0 = threadIdx.x, d1 = threadIdx.x + 256;
    const int r0 = blockIdx.x*8;
    f32x4 wa[4], wb[4];
    #pragma unroll
    for (int q = 0; q < 4; q++) {
        wa[q] = *(const f32x4*)(Wdt + d0*16 + q*4);
        wb[q] = *(const f32x4*)(Wdt + d1*16 + q*4);
    }
    const float b0 = bdt[d0], b1 = bdt[d1];
    #pragma unroll
    for (int rr = 0; rr < 8; rr++) {
        int row = r0 + rr;
        if (row >= ROWS) return;
        const f32x4* p = (const f32x4*)(dbc + (long)row*48);
        f32x4 t0 = p[0], t1 = p[1], t2 = p[2], t3 = p[3];
        float s0 = b0, s1 = b1;
        #pragma unroll
        for (int e = 0; e < 4; e++) {
            s0 += wa[0][e]*t0[e] + wa[1][e]*t1[e] + wa[2][e]*t2[e] + wa[3][e]*t3[e];
            s1 += wb[0][e]*t0[e] + wb[1][e]*t1[e] + wb[2][e]*t2[e] + wb[3][e]*t3[e];
        }
        float dl0 = (s0 > 20.f) ? s0 : log1pf(__expf(s0));
        float dl1 = (s1 > 20.f) ? s1 : log1pf(__expf(s1));
        deltab[(long)row*512 + d0] = (__bf16)dl0;
        deltab[(long)row*512 + d1] = (__bf16)dl1;
    }
}

// ---------------------------------------------------------------------------
// Patch rearrange + LayerNorm(256) + skip add; cls row q==0
// ---------------------------------------------------------------------------
__global__ __launch_bounds__(256) void rearrange_ln_cls(
    const __bf16* __restrict__ e_buf, const float* __restrict__ x,
    const float* __restrict__ cls_w, const float* __restrict__ cls_b,
    const float* __restrict__ ln_g, const float* __restrict__ ln_b,
    const float* __restrict__ skip, float* __restrict__ xx,
    __bf16* __restrict__ xxb)
{
    const int blk = blockIdx.x;
    const int b = blk / L_TOT;
    const int q = blk % L_TOT;
    const int c = threadIdx.x;

    if (q == 0) {
        __shared__ float xr[512];
        const float* xrow = x + (long)b*1025*512;
        xr[c] = xrow[c]; xr[c+256] = xrow[c+256];
        __syncthreads();
        float acc = cls_b[c];
        const float4* wrow = (const float4*)(cls_w + (long)c*512);
        #pragma unroll 8
        for (int m4 = 0; m4 < 128; m4++) {
            float4 wv = wrow[m4];
            float4 xv = *(const float4*)&xr[m4*4];
            acc += wv.x*xv.x + wv.y*xv.y + wv.z*xv.z + wv.w*xv.w;
        }
        long o = (long)b*L_TOT*256 + c;
        float v = acc + skip[o];
        xx[o] = v; xxb[o] = (__bf16)v;
        return;
    }
    const int t  = (q-1) >> 10;
    const int p  = (q-1) & 1023;
    const int h  = p >> 6;
    const int a  = (p >> 5) & 1;
    const int w  = (p >> 1) & 15;
    const int bb = p & 1;
    const long tok = (long)b*1024 + t*256 + h*16 + w;
    float v = (float)e_buf[tok*1024 + a*512 + bb*256 + c];

    float s = v, s2 = v*v;
    #pragma unroll
    for (int o = 32; o > 0; o >>= 1) { s += __shfl_xor(s, o); s2 += __shfl_xor(s2, o); }
    __shared__ float ps[4], ps2[4];
    __shared__ float mu_s, rs_s;
    const int wv = threadIdx.x >> 6;
    if ((threadIdx.x & 63) == 0) { ps[wv] = s; ps2[wv] = s2; }
    __syncthreads();
    if (threadIdx.x == 0) {
        float S = ps[0]+ps[1]+ps[2]+ps[3];
        float S2 = ps2[0]+ps2[1]+ps2[2]+ps2[3];
        float mu = S * (1.f/256.f);
        float var = S2 * (1.f/256.f) - mu*mu;
        mu_s = mu; rs_s = rsqrtf(var + 1e-5f);
    }
    __syncthreads();
    long o = ((long)b*L_TOT + q)*256 + c;
    float outv = (v - mu_s)*rs_s*ln_g[c] + ln_b[c] + skip[o];
    xx[o] = outv; xxb[o] = (__bf16)outv;
}

// ---------------------------------------------------------------------------
// Depthwise causal conv (k=4)+SiLU on d<512 -> xib; silu(z) on d>=512 -> zsb
// ---------------------------------------------------------------------------
__global__ __launch_bounds__(256) void conv_silu_split(
    const __bf16* __restrict__ xzb, const float* __restrict__ cw,
    const float* __restrict__ cb, __bf16* __restrict__ xib,
    __bf16* __restrict__ zsb)
{
    long idx = (long)blockIdx.x*256 + threadIdx.x;
    if (idx >= (long)ROWS*1024) return;
    int d = (int)(idx & 1023);
    long rl = idx >> 10;
    if (d < 512) {
        int l = (int)(rl % L_TOT);
        float acc = cb[d];
        #pragma unroll
        for (int k = 0; k < 4; k++) {
            int ls = l + k - 3;
            if (ls >= 0) acc += cw[d*4 + k] * (float)xzb[(rl + (k-3))*1024 + d];
        }
        xib[rl*512 + d] = (__bf16)siluf_(acc);
    } else {
        float z = (float)xzb[idx];
        zsb[rl*512 + (d - 512)] = (__bf16)siluf_(z);
    }
}

// ---------------------------------------------------------------------------
// Segmented scan: 4 threads per (b,d), 4 states each.  B,C read from dbc.
// ---------------------------------------------------------------------------
__global__ __launch_bounds__(256) void scan_p1(
    const __bf16* __restrict__ delta, const __bf16* __restrict__ xi,
    const float* __restrict__ dbc, const float* __restrict__ A_log,
    float* __restrict__ segH, float* __restrict__ segP)
{
    const int seg = blockIdx.x >> 4;
    const int t = ((blockIdx.x & 15) << 8) + threadIdx.x;  // 0..4095
    const int b = t >> 11;
    const int d = (t >> 2) & 511;
    const int ng = t & 3;
    f32x4 Al = *(const f32x4*)(A_log + d*16 + ng*4);
    float Ar[4] = {-__expf(Al[0]), -__expf(Al[1]), -__expf(Al[2]), -__expf(Al[3])};
    float h[4] = {0,0,0,0};
    float P[4] = {1,1,1,1};
    const int l0 = seg*SEGLEN;
    const int l1 = min(l0 + SEGLEN, L_TOT);
    for (int l = l0; l < l1; l++) {
        long base = (long)b*L_TOT + l;
        float dl = (float)delta[base*512 + d];
        float xv = (float)xi[base*512 + d];
        f32x4 Bv = *(const f32x4*)(dbc + base*48 + 16 + ng*4);
        float dx = dl*xv;
        #pragma unroll
        for (int n = 0; n < 4; n++) {
            float E = __expf(dl*Ar[n]);
            h[n] = h[n]*E + dx*Bv[n];
            P[n] *= E;
        }
    }
    long off = ((long)(seg*2 + b)*512 + d)*16 + ng*4;
    *(f32x4*)&segH[off] = f32x4{h[0],h[1],h[2],h[3]};
    *(f32x4*)&segP[off] = f32x4{P[0],P[1],P[2],P[3]};
}

__global__ __launch_bounds__(256) void scan_p2(
    float* __restrict__ segH, const float* __restrict__ segP)
{
    const int idx = blockIdx.x*256 + threadIdx.x;   // 16384
    float carry = 0.f;
    for (int s0 = 0; s0 < NSEG; s0 += 8) {
        float hh[8], pp[8];
        #pragma unroll
        for (int j = 0; j < 8; j++) {
            long o = (long)(s0+j)*16384 + idx;
            hh[j] = segH[o]; pp[j] = segP[o];
        }
        #pragma unroll
        for (int j = 0; j < 8; j++) {
            long o = (long)(s0+j)*16384 + idx;
            segH[o] = carry;
            carry = pp[j]*carry + hh[j];
        }
    }
}

__global__ __launch_bounds__(256) void scan_p3(
    const __bf16* __restrict__ delta, const __bf16* __restrict__ xi,
    const float* __restrict__ dbc, const float* __restrict__ A_log,
    const float* __restrict__ segH, const float* __restrict__ Dp,
    const __bf16* __restrict__ zsb, __bf16* __restrict__ yb)
{
    const int seg = blockIdx.x >> 4;
    const int t = ((blockIdx.x & 15) << 8) + threadIdx.x;
    const int b = t >> 11;
    const int d = (t >> 2) & 511;
    const int ng = t & 3;
    f32x4 Al = *(const f32x4*)(A_log + d*16 + ng*4);
    float Ar[4] = {-__expf(Al[0]), -__expf(Al[1]), -__expf(Al[2]), -__expf(Al[3])};
    long off = ((long)(seg*2 + b)*512 + d)*16 + ng*4;
    f32x4 h4 = *(const f32x4*)&segH[off];
    float h[4] = {h4[0], h4[1], h4[2], h4[3]};
    const float Dd = Dp[d];
    const int l0 = seg*SEGLEN;
    const int l1 = min(l0 + SEGLEN, L_TOT);
    for (int l = l0; l < l1; l++) {
        long base = (long)b*L_TOT + l;
        float dl = (float)delta[base*512 + d];
        float xv = (float)xi[base*512 + d];
        f32x4 Bv = *(const f32x4*)(dbc + base*48 + 16 + ng*4);
        f32x4 Cv = *(const f32x4*)(dbc + base*48 + 32 + ng*4);
        float dx = dl*xv;
        float y = 0.f;
        #pragma unroll
        for (int n = 0; n < 4; n++) {
            float E = __expf(dl*Ar[n]);
            h[n] = h[n]*E + dx*Bv[n];
            y += h[n]*Cv[n];
        }
        y += __shfl_xor(y, 1);
        y += __shfl_xor(y, 2);
        if (ng == 0) {
            float z = (float)zsb[base*512 + d];
            float yo = (y + xv*Dd) * z;
            yb[base*512 + d] = (__bf16)yo;
        }
    }
}

// ---------------------------------------------------------------------------
// BatchNorm over rows
// ---------------------------------------------------------------------------
__global__ void zero_stats(float* __restrict__ stats) { stats[threadIdx.x] = 0.f; }

__global__ __launch_bounds__(256) void bn_reduce(
    const float* __restrict__ xx, float* __restrict__ stats)
{
    const int c = threadIdx.x;
    float s = 0.f, s2 = 0.f;
    for (int r = blockIdx.x; r < ROWS; r += gridDim.x) {
        float v = xx[(long)r*256 + c];
        s += v; s2 += v*v;
    }
    atomicAdd(&stats[c], s);
    atomicAdd(&stats[256 + c], s2);
}

__global__ __launch_bounds__(256) void bn_apply(
    const float* __restrict__ xx, const float* __restrict__ stats,
    const float* __restrict__ g, const float* __restrict__ bta,
    float* __restrict__ out)
{
    long idx = (long)blockIdx.x*256 + threadIdx.x;
    if (idx == 0) out[(long)ROWS*256] = 1024.0f;
    if (idx >= (long)ROWS*256) return;
    int c = (int)(idx & 255);
    float mu = stats[c] * (1.f/ROWS);
    float var = stats[256 + c] * (1.f/ROWS) - mu*mu;
    out[idx] = (xx[idx] - mu)*rsqrtf(var + 1e-5f)*g[c] + bta[c];
}

// ---------------------------------------------------------------------------
extern "C" void kernel_launch(void* const* d_in, const int* in_sizes, int n_in,
                              void* d_out, int out_size, void* d_ws, size_t ws_size,
                              hipStream_t stream)
{
    const float* x        = (const float*)d_in[0];
    const float* skip     = (const float*)d_in[1];
    const float* exp_w    = (const float*)d_in[2];
    const float* ln_g     = (const float*)d_in[3];
    const float* ln_b     = (const float*)d_in[4];
    const float* cls_w    = (const float*)d_in[5];
    const float* cls_b    = (const float*)d_in[6];
    const float* in_proj_w= (const float*)d_in[7];
    const float* conv_w   = (const float*)d_in[8];
    const float* conv_b   = (const float*)d_in[9];
    const float* xproj_w  = (const float*)d_in[10];
    const float* dt_w     = (const float*)d_in[11];
    const float* dt_b     = (const float*)d_in[12];
    const float* A_log    = (const float*)d_in[13];
    const float* Dp       = (const float*)d_in[14];
    const float* out_w    = (const float*)d_in[15];
    const float* bn_g     = (const float*)d_in[16];
    const float* bn_b     = (const float*)d_in[17];

    float* ws = (float*)d_ws;
    float* xx    = ws;                       // 2,097,664 f32
    float* dbc   = xx + 2097664;             //   393,312 f32 [ROWS,48]
    float* segH  = dbc + 393312;             // 2,097,152 f32
    float* segP  = segH + 2097152;           // 2,097,152 f32
    float* stats = segP + 2097152;           //       512 f32
    __bf16* expWb = (__bf16*)(stats + 512);  //   524,288
    __bf16* inWb  = expWb + 524288;          //   524,288 (2 layers)
    __bf16* outWb = inWb + 524288;           //   262,144 (2 layers)
    __bf16* xpWb  = outWb + 262144;          //    49,152 (2 layers x 48x512)
    __bf16* xxb   = xpWb + 49152;            // 2,097,664
    __bf16* xzb   = xxb + 2097664;           // 8,390,656 [ROWS,1024]
    __bf16* e_b   = xzb;                     // alias (pre-loop): 2,097,152
    __bf16* xib   = xzb + 8390656;           // 4,195,328
    __bf16* Axb   = xib;                     // alias (pre-loop): 1,048,576
    __bf16* zsb   = xib + 4195328;           // 4,195,328
    __bf16* deltab= zsb + 4195328;           // 4,195,328
    __bf16* yb    = deltab + 4195328;        // 4,195,328
    float* out    = (float*)d_out;

    cvt4<<<(1359872/8 + 255)/256, 256, 0, stream>>>(
        exp_w, in_proj_w, out_w, xproj_w, expWb, inWb, outWb, xpWb);
    cvt_gather_x<<<(1048576/8)/256, 256, 0, stream>>>(x, Axb);

    gemm_bf16<2><<<dim3(16, 16), 256, 0, stream>>>(
        Axb, expWb, nullptr, e_b, 2048, 1024, 512);
    rearrange_ln_cls<<<ROWS, 256, 0, stream>>>(
        e_b, x, cls_w, cls_b, ln_g, ln_b, skip, xx, xxb);

    for (int layer = 0; layer < 2; layer++) {
        gemm_bf16<2><<<dim3(16, 65), 256, 0, stream>>>(
            xxb, inWb + layer*262144, nullptr, xzb, ROWS, 1024, 256);
        conv_silu_split<<<((long)ROWS*1024 + 255)/256, 256, 0, stream>>>(
            xzb, conv_w + layer*512*4, conv_b + layer*512, xib, zsb);
        gemm_dbc<<<(ROWS + 63)/64, 128, 0, stream>>>(
            xib, xpWb + layer*24576, dbc, ROWS);
        delta_k<<<(ROWS + 7)/8, 256, 0, stream>>>(
            dbc, dt_w + layer*512*16, dt_b + layer*512, deltab);
        scan_p1<<<NSEG*16, 256, 0, stream>>>(
            deltab, xib, dbc, A_log + layer*512*16, segH, segP);
        scan_p2<<<64, 256, 0, stream>>>(segH, segP);
        scan_p3<<<NSEG*16, 256, 0, stream>>>(
            deltab, xib, dbc, A_log + layer*512*16, segH, Dp + layer*512, zsb, yb);
        if (layer == 0) {
            gemm_bf16<1><<<dim3(4, 65), 256, 0, stream>>>(
                yb, outWb, xx, xxb, ROWS, 256, 512);
        } else {
            gemm_bf16<0><<<dim3(4, 65), 256, 0, stream>>>(
                yb, outWb + 131072, xx, nullptr, ROWS, 256, 512);
        }
    }

    zero_stats<<<1, 512, 0, stream>>>(stats);
    bn_reduce<<<128, 256, 0, stream>>>(xx, stats);
    bn_apply<<<((long)ROWS*256 + 255)/256 + 1, 256, 0, stream>>>(xx, stats, bn_g, bn_b, out);
}

// Round 4
// 466.904 us; speedup vs baseline: 1.6515x; 1.0274x over previous
//
#include <hip/hip_runtime.h>
#include <hip/hip_bf16.h>
#include <math.h>

#define L_TOT 4097
#define BSZ 2
#define ROWS (BSZ*L_TOT)   // 8194
#define NSEG 128
#define SEGLEN 33          // 128*33 = 4224 >= 4097

typedef __bf16 bf16x8 __attribute__((ext_vector_type(8)));
typedef float  f32x4  __attribute__((ext_vector_type(4)));
#define ASTR 56            // LDS row stride (bf16): 112B

__device__ __forceinline__ float sigmoidf_(float v){ return 1.0f/(1.0f+__expf(-v)); }
__device__ __forceinline__ float siluf_(float v){ return v * sigmoidf_(v); }
__device__ __forceinline__ unsigned short bfbits(float f){
    __bf16 h = (__bf16)f;
    return __builtin_bit_cast(unsigned short, h);
}

// ---------------------------------------------------------------------------
// f32 -> bf16 weight conversion (4 tensors in one launch)
// ---------------------------------------------------------------------------
__global__ __launch_bounds__(256) void cvt4(
    const float* __restrict__ w0, const float* __restrict__ w1,
    const float* __restrict__ w2, const float* __restrict__ w3,
    __bf16* __restrict__ o0, __bf16* __restrict__ o1,
    __bf16* __restrict__ o2, __bf16* __restrict__ o3)
{
    long i = ((long)blockIdx.x*256 + threadIdx.x)*8;
    const float* src; __bf16* dst; long off;
    if (i < 524288)        { src = w0; dst = o0; off = i; }
    else if (i < 1048576)  { src = w1; dst = o1; off = i - 524288; }
    else if (i < 1310720)  { src = w2; dst = o2; off = i - 1048576; }
    else if (i < 1359872)  { src = w3; dst = o3; off = i - 1310720; }
    else return;
    float4 a = *(const float4*)(src+off), b = *(const float4*)(src+off+4);
    bf16x8 o;
    o[0]=(__bf16)a.x; o[1]=(__bf16)a.y; o[2]=(__bf16)a.z; o[3]=(__bf16)a.w;
    o[4]=(__bf16)b.x; o[5]=(__bf16)b.y; o[6]=(__bf16)b.z; o[7]=(__bf16)b.w;
    *(bf16x8*)(dst+off) = o;
}

__global__ __launch_bounds__(256) void cvt_gather_x(
    const float* __restrict__ x, __bf16* __restrict__ out)
{
    long i = ((long)blockIdx.x*256 + threadIdx.x)*8;
    if (i >= 2048L*512) return;
    int row = (int)(i >> 9), col = (int)(i & 511);
    long srow = row + (row >> 10) + 1;
    const float* src = x + srow*512 + col;
    float4 a = *(const float4*)src, b = *(const float4*)(src+4);
    bf16x8 o;
    o[0]=(__bf16)a.x; o[1]=(__bf16)a.y; o[2]=(__bf16)a.z; o[3]=(__bf16)a.w;
    o[4]=(__bf16)b.x; o[5]=(__bf16)b.y; o[6]=(__bf16)b.z; o[7]=(__bf16)b.w;
    *(bf16x8*)(out+i) = o;
}

// ---------------------------------------------------------------------------
// bf16 MFMA GEMM: C[M,N] = A[M,K] * W[N,K]^T, f32 accumulate.
// BM=128, BN=64, BK=32, 256 threads. SMODE: 0=f32 C, 1=both, 2=bf16 C2 only.
// ---------------------------------------------------------------------------
template<int SMODE>
__global__ __launch_bounds__(256) void gemm_bf16(
    const __bf16* __restrict__ A, const __bf16* __restrict__ W,
    float* __restrict__ C, __bf16* __restrict__ C2, int M, int N, int K)
{
    __shared__ __bf16 Als[128*ASTR];
    __shared__ __bf16 Wls[64*ASTR];
    const int tid = threadIdx.x;
    const int lane = tid & 63, w = tid >> 6;
    const int n0 = blockIdx.x*64, m0 = blockIdx.y*128;

    f32x4 zero = {0.f,0.f,0.f,0.f};
    f32x4 acc[2][4];
    #pragma unroll
    for (int i=0;i<2;i++)
        #pragma unroll
        for (int j=0;j<4;j++) acc[i][j] = zero;

    const int arow = tid >> 1, ahalf = tid & 1;
    const int wrow = tid >> 2, wseg = tid & 3;
    const int fr = lane & 15, fc = lane >> 4;

    for (int k0 = 0; k0 < K; k0 += 32) {
        bf16x8 av0 = {}, av1 = {};
        if (m0 + arow < M) {
            const __bf16* src = A + (long)(m0+arow)*K + k0 + ahalf*16;
            av0 = *(const bf16x8*)src;
            av1 = *(const bf16x8*)(src+8);
        }
        bf16x8 wv = *(const bf16x8*)(W + (long)(n0+wrow)*K + k0 + wseg*8);
        __syncthreads();
        *(bf16x8*)&Als[arow*ASTR + ahalf*16]     = av0;
        *(bf16x8*)&Als[arow*ASTR + ahalf*16 + 8] = av1;
        *(bf16x8*)&Wls[wrow*ASTR + wseg*8]       = wv;
        __syncthreads();

        bf16x8 a0 = *(const bf16x8*)&Als[(w*32 +      fr)*ASTR + fc*8];
        bf16x8 a1 = *(const bf16x8*)&Als[(w*32 + 16 + fr)*ASTR + fc*8];
        #pragma unroll
        for (int j = 0; j < 4; j++) {
            bf16x8 bv = *(const bf16x8*)&Wls[(j*16 + fr)*ASTR + fc*8];
            acc[0][j] = __builtin_amdgcn_mfma_f32_16x16x32_bf16(a0, bv, acc[0][j], 0,0,0);
            acc[1][j] = __builtin_amdgcn_mfma_f32_16x16x32_bf16(a1, bv, acc[1][j], 0,0,0);
        }
    }
    #pragma unroll
    for (int i = 0; i < 2; i++) {
        #pragma unroll
        for (int rr = 0; rr < 4; rr++) {
            int grow = m0 + w*32 + i*16 + fc*4 + rr;
            if (grow < M) {
                #pragma unroll
                for (int j = 0; j < 4; j++) {
                    float v = acc[i][j][rr];
                    long o = (long)grow*N + n0 + j*16 + fr;
                    if (SMODE != 2) C[o] = v;
                    if (SMODE != 0) C2[o] = (__bf16)v;
                }
            }
        }
    }
}

// ---------------------------------------------------------------------------
// dbc GEMM: dbc[M,48] = xib[M,512] @ Wx[48,512]^T.  BM=64, 128 threads
// ---------------------------------------------------------------------------
__global__ __launch_bounds__(128) void gemm_dbc(
    const __bf16* __restrict__ A, const __bf16* __restrict__ W,
    float* __restrict__ C, int M)
{
    __shared__ __bf16 Als[64*ASTR];
    __shared__ __bf16 Wls[48*ASTR];
    const int tid = threadIdx.x;
    const int lane = tid & 63, w = tid >> 6;
    const int m0 = blockIdx.x*64;
    f32x4 zero = {0.f,0.f,0.f,0.f};
    f32x4 acc[2][3];
    #pragma unroll
    for (int i=0;i<2;i++)
        #pragma unroll
        for (int j=0;j<3;j++) acc[i][j] = zero;

    const int arow = tid >> 1, ahalf = tid & 1;
    const int fr = lane & 15, fc = lane >> 4;

    for (int k0 = 0; k0 < 512; k0 += 32) {
        bf16x8 av0 = {}, av1 = {};
        if (m0 + arow < M) {
            const __bf16* src = A + (long)(m0+arow)*512 + k0 + ahalf*16;
            av0 = *(const bf16x8*)src;
            av1 = *(const bf16x8*)(src+8);
        }
        bf16x8 wv0 = {}, wv1 = {};
        if (tid < 96) {
            const __bf16* src = W + (long)(tid>>1)*512 + k0 + (tid&1)*16;
            wv0 = *(const bf16x8*)src;
            wv1 = *(const bf16x8*)(src+8);
        }
        __syncthreads();
        *(bf16x8*)&Als[arow*ASTR + ahalf*16]     = av0;
        *(bf16x8*)&Als[arow*ASTR + ahalf*16 + 8] = av1;
        if (tid < 96) {
            *(bf16x8*)&Wls[(tid>>1)*ASTR + (tid&1)*16]     = wv0;
            *(bf16x8*)&Wls[(tid>>1)*ASTR + (tid&1)*16 + 8] = wv1;
        }
        __syncthreads();

        bf16x8 a0 = *(const bf16x8*)&Als[(w*32 +      fr)*ASTR + fc*8];
        bf16x8 a1 = *(const bf16x8*)&Als[(w*32 + 16 + fr)*ASTR + fc*8];
        #pragma unroll
        for (int j = 0; j < 3; j++) {
            bf16x8 bv = *(const bf16x8*)&Wls[(j*16 + fr)*ASTR + fc*8];
            acc[0][j] = __builtin_amdgcn_mfma_f32_16x16x32_bf16(a0, bv, acc[0][j], 0,0,0);
            acc[1][j] = __builtin_amdgcn_mfma_f32_16x16x32_bf16(a1, bv, acc[1][j], 0,0,0);
        }
    }
    #pragma unroll
    for (int i = 0; i < 2; i++) {
        #pragma unroll
        for (int rr = 0; rr < 4; rr++) {
            int grow = m0 + w*32 + i*16 + fc*4 + rr;
            if (grow < M) {
                #pragma unroll
                for (int j = 0; j < 3; j++)
                    C[(long)grow*48 + j*16 + fr] = acc[i][j][rr];
            }
        }
    }
}

// ---------------------------------------------------------------------------
// delta: softplus(dbc[:, :16] @ Wdt^T + bdt); pack (delta,xi) bf16 pair -> u32
// ---------------------------------------------------------------------------
__global__ __launch_bounds__(256) void delta_k(
    const float* __restrict__ dbc, const float* __restrict__ Wdt,
    const float* __restrict__ bdt, const __bf16* __restrict__ xib,
    unsigned* __restrict__ pdx)
{
    const int d0 = threadIdx.x, d1 = threadIdx.x + 256;
    const int r0 = blockIdx.x*8;
    f32x4 wa[4], wb[4];
    #pragma unroll
    for (int q = 0; q < 4; q++) {
        wa[q] = *(const f32x4*)(Wdt + d0*16 + q*4);
        wb[q] = *(const f32x4*)(Wdt + d1*16 + q*4);
    }
    const float b0 = bdt[d0], b1 = bdt[d1];
    #pragma unroll
    for (int rr = 0; rr < 8; rr++) {
        int row = r0 + rr;
        if (row >= ROWS) return;
        const f32x4* p = (const f32x4*)(dbc + (long)row*48);
        f32x4 t0 = p[0], t1 = p[1], t2 = p[2], t3 = p[3];
        float s0 = b0, s1 = b1;
        #pragma unroll
        for (int e = 0; e < 4; e++) {
            s0 += wa[0][e]*t0[e] + wa[1][e]*t1[e] + wa[2][e]*t2[e] + wa[3][e]*t3[e];
            s1 += wb[0][e]*t0[e] + wb[1][e]*t1[e] + wb[2][e]*t2[e] + wb[3][e]*t3[e];
        }
        float dl0 = (s0 > 20.f) ? s0 : log1pf(__expf(s0));
        float dl1 = (s1 > 20.f) ? s1 : log1pf(__expf(s1));
        unsigned x0 = __builtin_bit_cast(unsigned short, xib[(long)row*512 + d0]);
        unsigned x1 = __builtin_bit_cast(unsigned short, xib[(long)row*512 + d1]);
        pdx[(long)row*512 + d0] = (unsigned)bfbits(dl0) | (x0 << 16);
        pdx[(long)row*512 + d1] = (unsigned)bfbits(dl1) | (x1 << 16);
    }
}

// ---------------------------------------------------------------------------
// Patch rearrange + LayerNorm(256) + skip add; cls row q==0
// ---------------------------------------------------------------------------
__global__ __launch_bounds__(256) void rearrange_ln_cls(
    const __bf16* __restrict__ e_buf, const float* __restrict__ x,
    const float* __restrict__ cls_w, const float* __restrict__ cls_b,
    const float* __restrict__ ln_g, const float* __restrict__ ln_b,
    const float* __restrict__ skip, float* __restrict__ xx,
    __bf16* __restrict__ xxb)
{
    const int blk = blockIdx.x;
    const int b = blk / L_TOT;
    const int q = blk % L_TOT;
    const int c = threadIdx.x;

    if (q == 0) {
        __shared__ float xr[512];
        const float* xrow = x + (long)b*1025*512;
        xr[c] = xrow[c]; xr[c+256] = xrow[c+256];
        __syncthreads();
        float acc = cls_b[c];
        const float4* wrow = (const float4*)(cls_w + (long)c*512);
        #pragma unroll 8
        for (int m4 = 0; m4 < 128; m4++) {
            float4 wv = wrow[m4];
            float4 xv = *(const float4*)&xr[m4*4];
            acc += wv.x*xv.x + wv.y*xv.y + wv.z*xv.z + wv.w*xv.w;
        }
        long o = (long)b*L_TOT*256 + c;
        float v = acc + skip[o];
        xx[o] = v; xxb[o] = (__bf16)v;
        return;
    }
    const int t  = (q-1) >> 10;
    const int p  = (q-1) & 1023;
    const int h  = p >> 6;
    const int a  = (p >> 5) & 1;
    const int w  = (p >> 1) & 15;
    const int bb = p & 1;
    const long tok = (long)b*1024 + t*256 + h*16 + w;
    float v = (float)e_buf[tok*1024 + a*512 + bb*256 + c];

    float s = v, s2 = v*v;
    #pragma unroll
    for (int o = 32; o > 0; o >>= 1) { s += __shfl_xor(s, o); s2 += __shfl_xor(s2, o); }
    __shared__ float ps[4], ps2[4];
    __shared__ float mu_s, rs_s;
    const int wv = threadIdx.x >> 6;
    if ((threadIdx.x & 63) == 0) { ps[wv] = s; ps2[wv] = s2; }
    __syncthreads();
    if (threadIdx.x == 0) {
        float S = ps[0]+ps[1]+ps[2]+ps[3];
        float S2 = ps2[0]+ps2[1]+ps2[2]+ps2[3];
        float mu = S * (1.f/256.f);
        float var = S2 * (1.f/256.f) - mu*mu;
        mu_s = mu; rs_s = rsqrtf(var + 1e-5f);
    }
    __syncthreads();
    long o = ((long)b*L_TOT + q)*256 + c;
    float outv = (v - mu_s)*rs_s*ln_g[c] + ln_b[c] + skip[o];
    xx[o] = outv; xxb[o] = (__bf16)outv;
}

// ---------------------------------------------------------------------------
// Depthwise causal conv (k=4)+SiLU, vectorized: thread = (row, 8-chan chunk)
// chunk<64 -> conv on x half; chunk>=64 -> silu(z) half
// ---------------------------------------------------------------------------
__global__ __launch_bounds__(256) void conv_silu_split(
    const __bf16* __restrict__ xzb, const float* __restrict__ cw,
    const float* __restrict__ cb, __bf16* __restrict__ xib,
    __bf16* __restrict__ zsb)
{
    long tid = (long)blockIdx.x*256 + threadIdx.x;
    if (tid >= (long)ROWS*128) return;
    int chunk = (int)(tid & 127);
    long rl = tid >> 7;
    if (chunk < 64) {
        int d0 = chunk*8;
        int l = (int)(rl % L_TOT);
        float acc[8];
        #pragma unroll
        for (int e = 0; e < 8; e++) acc[e] = cb[d0+e];
        #pragma unroll
        for (int k = 0; k < 4; k++) {
            int ls = l + k - 3;
            if (ls >= 0) {
                bf16x8 v = *(const bf16x8*)&xzb[(rl + (k-3))*1024 + d0];
                #pragma unroll
                for (int e = 0; e < 8; e++)
                    acc[e] += cw[(d0+e)*4 + k] * (float)v[e];
            }
        }
        bf16x8 o;
        #pragma unroll
        for (int e = 0; e < 8; e++) o[e] = (__bf16)siluf_(acc[e]);
        *(bf16x8*)&xib[rl*512 + d0] = o;
    } else {
        int d0 = (chunk - 64)*8;
        bf16x8 v = *(const bf16x8*)&xzb[rl*1024 + 512 + d0];
        bf16x8 o;
        #pragma unroll
        for (int e = 0; e < 8; e++) o[e] = (__bf16)siluf_((float)v[e]);
        *(bf16x8*)&zsb[rl*512 + d0] = o;
    }
}

// ---------------------------------------------------------------------------
// Segmented scan: 4 threads per (b,d), 4 states each.  (delta,xi) from pdx.
// ---------------------------------------------------------------------------
__global__ __launch_bounds__(256) void scan_p1(
    const unsigned* __restrict__ pdx,
    const float* __restrict__ dbc, const float* __restrict__ A_log,
    float* __restrict__ segH, float* __restrict__ segP)
{
    const int seg = blockIdx.x >> 4;
    const int t = ((blockIdx.x & 15) << 8) + threadIdx.x;
    const int b = t >> 11;
    const int d = (t >> 2) & 511;
    const int ng = t & 3;
    f32x4 Al = *(const f32x4*)(A_log + d*16 + ng*4);
    float Ar[4] = {-__expf(Al[0]), -__expf(Al[1]), -__expf(Al[2]), -__expf(Al[3])};
    float h[4] = {0,0,0,0};
    float P[4] = {1,1,1,1};
    const int l0 = seg*SEGLEN;
    const int l1 = min(l0 + SEGLEN, L_TOT);
    for (int l = l0; l < l1; l++) {
        long base = (long)b*L_TOT + l;
        unsigned v = pdx[base*512 + d];
        float dl = __uint_as_float(v << 16);
        float xv = __uint_as_float(v & 0xffff0000u);
        f32x4 Bv = *(const f32x4*)(dbc + base*48 + 16 + ng*4);
        float dx = dl*xv;
        #pragma unroll
        for (int n = 0; n < 4; n++) {
            float E = __expf(dl*Ar[n]);
            h[n] = h[n]*E + dx*Bv[n];
            P[n] *= E;
        }
    }
    long off = ((long)(seg*2 + b)*512 + d)*16 + ng*4;
    *(f32x4*)&segH[off] = f32x4{h[0],h[1],h[2],h[3]};
    *(f32x4*)&segP[off] = f32x4{P[0],P[1],P[2],P[3]};
}

__global__ __launch_bounds__(256) void scan_p2(
    float* __restrict__ segH, const float* __restrict__ segP)
{
    const int idx = blockIdx.x*256 + threadIdx.x;   // 16384
    float carry = 0.f;
    for (int s0 = 0; s0 < NSEG; s0 += 8) {
        float hh[8], pp[8];
        #pragma unroll
        for (int j = 0; j < 8; j++) {
            long o = (long)(s0+j)*16384 + idx;
            hh[j] = segH[o]; pp[j] = segP[o];
        }
        #pragma unroll
        for (int j = 0; j < 8; j++) {
            long o = (long)(s0+j)*16384 + idx;
            segH[o] = carry;
            carry = pp[j]*carry + hh[j];
        }
    }
}

__global__ __launch_bounds__(256) void scan_p3(
    const unsigned* __restrict__ pdx,
    const float* __restrict__ dbc, const float* __restrict__ A_log,
    const float* __restrict__ segH, const float* __restrict__ Dp,
    const __bf16* __restrict__ zsb, __bf16* __restrict__ yb)
{
    const int seg = blockIdx.x >> 4;
    const int t = ((blockIdx.x & 15) << 8) + threadIdx.x;
    const int b = t >> 11;
    const int d = (t >> 2) & 511;
    const int ng = t & 3;
    f32x4 Al = *(const f32x4*)(A_log + d*16 + ng*4);
    float Ar[4] = {-__expf(Al[0]), -__expf(Al[1]), -__expf(Al[2]), -__expf(Al[3])};
    long off = ((long)(seg*2 + b)*512 + d)*16 + ng*4;
    f32x4 h4 = *(const f32x4*)&segH[off];
    float h[4] = {h4[0], h4[1], h4[2], h4[3]};
    const float Dd = Dp[d];
    const int l0 = seg*SEGLEN;
    const int l1 = min(l0 + SEGLEN, L_TOT);
    for (int l = l0; l < l1; l++) {
        long base = (long)b*L_TOT + l;
        unsigned v = pdx[base*512 + d];
        float dl = __uint_as_float(v << 16);
        float xv = __uint_as_float(v & 0xffff0000u);
        f32x4 Bv = *(const f32x4*)(dbc + base*48 + 16 + ng*4);
        f32x4 Cv = *(const f32x4*)(dbc + base*48 + 32 + ng*4);
        float dx = dl*xv;
        float y = 0.f;
        #pragma unroll
        for (int n = 0; n < 4; n++) {
            float E = __expf(dl*Ar[n]);
            h[n] = h[n]*E + dx*Bv[n];
            y += h[n]*Cv[n];
        }
        y += __shfl_xor(y, 1);
        y += __shfl_xor(y, 2);
        if (ng == 0) {
            float z = (float)zsb[base*512 + d];
            float yo = (y + xv*Dd) * z;
            yb[base*512 + d] = (__bf16)yo;
        }
    }
}

// ---------------------------------------------------------------------------
// BatchNorm over rows
// ---------------------------------------------------------------------------
__global__ void zero_stats(float* __restrict__ stats) { stats[threadIdx.x] = 0.f; }

__global__ __launch_bounds__(256) void bn_reduce(
    const float* __restrict__ xx, float* __restrict__ stats)
{
    const int c = threadIdx.x;
    float s = 0.f, s2 = 0.f;
    for (int r = blockIdx.x; r < ROWS; r += gridDim.x) {
        float v = xx[(long)r*256 + c];
        s += v; s2 += v*v;
    }
    atomicAdd(&stats[c], s);
    atomicAdd(&stats[256 + c], s2);
}

__global__ __launch_bounds__(256) void bn_apply(
    const float* __restrict__ xx, const float* __restrict__ stats,
    const float* __restrict__ g, const float* __restrict__ bta,
    float* __restrict__ out)
{
    long idx = (long)blockIdx.x*256 + threadIdx.x;
    if (idx == 0) out[(long)ROWS*256] = 1024.0f;
    if (idx >= (long)ROWS*256) return;
    int c = (int)(idx & 255);
    float mu = stats[c] * (1.f/ROWS);
    float var = stats[256 + c] * (1.f/ROWS) - mu*mu;
    out[idx] = (xx[idx] - mu)*rsqrtf(var + 1e-5f)*g[c] + bta[c];
}

// ---------------------------------------------------------------------------
extern "C" void kernel_launch(void* const* d_in, const int* in_sizes, int n_in,
                              void* d_out, int out_size, void* d_ws, size_t ws_size,
                              hipStream_t stream)
{
    const float* x        = (const float*)d_in[0];
    const float* skip     = (const float*)d_in[1];
    const float* exp_w    = (const float*)d_in[2];
    const float* ln_g     = (const float*)d_in[3];
    const float* ln_b     = (const float*)d_in[4];
    const float* cls_w    = (const float*)d_in[5];
    const float* cls_b    = (const float*)d_in[6];
    const float* in_proj_w= (const float*)d_in[7];
    const float* conv_w   = (const float*)d_in[8];
    const float* conv_b   = (const float*)d_in[9];
    const float* xproj_w  = (const float*)d_in[10];
    const float* dt_w     = (const float*)d_in[11];
    const float* dt_b     = (const float*)d_in[12];
    const float* A_log    = (const float*)d_in[13];
    const float* Dp       = (const float*)d_in[14];
    const float* out_w    = (const float*)d_in[15];
    const float* bn_g     = (const float*)d_in[16];
    const float* bn_b     = (const float*)d_in[17];

    float* ws = (float*)d_ws;
    float* xx    = ws;                       // 2,097,664 f32
    float* dbc   = xx + 2097664;             //   393,312 f32
    float* segH  = dbc + 393312;             // 2,097,152 f32
    float* segP  = segH + 2097152;           // 2,097,152 f32
    float* stats = segP + 2097152;           //       512 f32
    unsigned* pdx = (unsigned*)(stats + 512);// 4,195,328 u32
    __bf16* expWb = (__bf16*)(pdx + 4195328);//   524,288
    __bf16* inWb  = expWb + 524288;          //   524,288
    __bf16* outWb = inWb + 524288;           //   262,144
    __bf16* xpWb  = outWb + 262144;          //    49,152
    __bf16* xxb   = xpWb + 49152;            // 2,097,664
    __bf16* xzb   = xxb + 2097664;           // 8,390,656
    __bf16* e_b   = xzb;                     // alias (pre-loop)
    __bf16* xib   = xzb + 8390656;           // 4,195,328
    __bf16* Axb   = xib;                     // alias (pre-loop)
    __bf16* zsb   = xib + 4195328;           // 4,195,328
    __bf16* yb    = zsb + 4195328;           // 4,195,328
    float* out    = (float*)d_out;

    cvt4<<<(1359872/8 + 255)/256, 256, 0, stream>>>(
        exp_w, in_proj_w, out_w, xproj_w, expWb, inWb, outWb, xpWb);
    cvt_gather_x<<<(1048576/8)/256, 256, 0, stream>>>(x, Axb);

    gemm_bf16<2><<<dim3(16, 16), 256, 0, stream>>>(
        Axb, expWb, nullptr, e_b, 2048, 1024, 512);
    rearrange_ln_cls<<<ROWS, 256, 0, stream>>>(
        e_b, x, cls_w, cls_b, ln_g, ln_b, skip, xx, xxb);

    for (int layer = 0; layer < 2; layer++) {
        gemm_bf16<2><<<dim3(16, 65), 256, 0, stream>>>(
            xxb, inWb + layer*262144, nullptr, xzb, ROWS, 1024, 256);
        conv_silu_split<<<((long)ROWS*128 + 255)/256, 256, 0, stream>>>(
            xzb, conv_w + layer*512*4, conv_b + layer*512, xib, zsb);
        gemm_dbc<<<(ROWS + 63)/64, 128, 0, stream>>>(
            xib, xpWb + layer*24576, dbc, ROWS);
        delta_k<<<(ROWS + 7)/8, 256, 0, stream>>>(
            dbc, dt_w + layer*512*16, dt_b + layer*512, xib, pdx);
        scan_p1<<<NSEG*16, 256, 0, stream>>>(
            pdx, dbc, A_log + layer*512*16, segH, segP);
        scan_p2<<<64, 256, 0, stream>>>(segH, segP);
        scan_p3<<<NSEG*16, 256, 0, stream>>>(
            pdx, dbc, A_log + layer*512*16, segH, Dp + layer*512, zsb, yb);
        if (layer == 0) {
            gemm_bf16<1><<<dim3(4, 65), 256, 0, stream>>>(
                yb, outWb, xx, xxb, ROWS, 256, 512);
        } else {
            gemm_bf16<0><<<dim3(4, 65), 256, 0, stream>>>(
                yb, outWb + 131072, xx, nullptr, ROWS, 256, 512);
        }
    }

    zero_stats<<<1, 512, 0, stream>>>(stats);
    bn_reduce<<<128, 256, 0, stream>>>(xx, stats);
    bn_apply<<<((long)ROWS*256 + 255)/256 + 1, 256, 0, stream>>>(xx, stats, bn_g, bn_b, out);
}

// Round 5
// 406.932 us; speedup vs baseline: 1.8949x; 1.1474x over previous
//
#include <hip/hip_runtime.h>
#include <hip/hip_bf16.h>
#include <math.h>

#define L_TOT 4097
#define BSZ 2
#define ROWS (BSZ*L_TOT)   // 8194
#define NSEG 128
#define SEGLEN 33          // 128*33 = 4224 >= 4097

typedef __bf16 bf16x8 __attribute__((ext_vector_type(8)));
typedef float  f32x4  __attribute__((ext_vector_type(4)));
#define ASTR 56            // LDS row stride (bf16) for BK=32 tiles
#define AST2 72            // LDS row stride (bf16) for BK=64 tiles

__device__ __forceinline__ float sigmoidf_(float v){ return 1.0f/(1.0f+__expf(-v)); }
__device__ __forceinline__ float siluf_(float v){ return v * sigmoidf_(v); }
__device__ __forceinline__ unsigned short bfbits(float f){
    __bf16 h = (__bf16)f;
    return __builtin_bit_cast(unsigned short, h);
}

// ---------------------------------------------------------------------------
// f32 -> bf16 weight conversion (4 tensors in one launch)
// ---------------------------------------------------------------------------
__global__ __launch_bounds__(256) void cvt4(
    const float* __restrict__ w0, const float* __restrict__ w1,
    const float* __restrict__ w2, const float* __restrict__ w3,
    __bf16* __restrict__ o0, __bf16* __restrict__ o1,
    __bf16* __restrict__ o2, __bf16* __restrict__ o3)
{
    long i = ((long)blockIdx.x*256 + threadIdx.x)*8;
    const float* src; __bf16* dst; long off;
    if (i < 524288)        { src = w0; dst = o0; off = i; }
    else if (i < 1048576)  { src = w1; dst = o1; off = i - 524288; }
    else if (i < 1310720)  { src = w2; dst = o2; off = i - 1048576; }
    else if (i < 1359872)  { src = w3; dst = o3; off = i - 1310720; }
    else return;
    float4 a = *(const float4*)(src+off), b = *(const float4*)(src+off+4);
    bf16x8 o;
    o[0]=(__bf16)a.x; o[1]=(__bf16)a.y; o[2]=(__bf16)a.z; o[3]=(__bf16)a.w;
    o[4]=(__bf16)b.x; o[5]=(__bf16)b.y; o[6]=(__bf16)b.z; o[7]=(__bf16)b.w;
    *(bf16x8*)(dst+off) = o;
}

__global__ __launch_bounds__(256) void cvt_gather_x(
    const float* __restrict__ x, __bf16* __restrict__ out)
{
    long i = ((long)blockIdx.x*256 + threadIdx.x)*8;
    if (i >= 2048L*512) return;
    int row = (int)(i >> 9), col = (int)(i & 511);
    long srow = row + (row >> 10) + 1;
    const float* src = x + srow*512 + col;
    float4 a = *(const float4*)src, b = *(const float4*)(src+4);
    bf16x8 o;
    o[0]=(__bf16)a.x; o[1]=(__bf16)a.y; o[2]=(__bf16)a.z; o[3]=(__bf16)a.w;
    o[4]=(__bf16)b.x; o[5]=(__bf16)b.y; o[6]=(__bf16)b.z; o[7]=(__bf16)b.w;
    *(bf16x8*)(out+i) = o;
}

// ---------------------------------------------------------------------------
// bf16 MFMA GEMM (BM=128,BN=64,BK=32): C[M,N] = A[M,K]*W[N,K]^T
// SMODE: 0=f32 C, 1=both, 2=bf16 C2 only.
// ---------------------------------------------------------------------------
template<int SMODE>
__global__ __launch_bounds__(256) void gemm_bf16(
    const __bf16* __restrict__ A, const __bf16* __restrict__ W,
    float* __restrict__ C, __bf16* __restrict__ C2, int M, int N, int K)
{
    __shared__ __bf16 Als[128*ASTR];
    __shared__ __bf16 Wls[64*ASTR];
    const int tid = threadIdx.x;
    const int lane = tid & 63, w = tid >> 6;
    const int n0 = blockIdx.x*64, m0 = blockIdx.y*128;

    f32x4 acc[2][4] = {};
    const int arow = tid >> 1, ahalf = tid & 1;
    const int wrow = tid >> 2, wseg = tid & 3;
    const int fr = lane & 15, fc = lane >> 4;

    for (int k0 = 0; k0 < K; k0 += 32) {
        bf16x8 av0 = {}, av1 = {};
        if (m0 + arow < M) {
            const __bf16* src = A + (long)(m0+arow)*K + k0 + ahalf*16;
            av0 = *(const bf16x8*)src;
            av1 = *(const bf16x8*)(src+8);
        }
        bf16x8 wv = *(const bf16x8*)(W + (long)(n0+wrow)*K + k0 + wseg*8);
        __syncthreads();
        *(bf16x8*)&Als[arow*ASTR + ahalf*16]     = av0;
        *(bf16x8*)&Als[arow*ASTR + ahalf*16 + 8] = av1;
        *(bf16x8*)&Wls[wrow*ASTR + wseg*8]       = wv;
        __syncthreads();

        bf16x8 a0 = *(const bf16x8*)&Als[(w*32 +      fr)*ASTR + fc*8];
        bf16x8 a1 = *(const bf16x8*)&Als[(w*32 + 16 + fr)*ASTR + fc*8];
        #pragma unroll
        for (int j = 0; j < 4; j++) {
            bf16x8 bv = *(const bf16x8*)&Wls[(j*16 + fr)*ASTR + fc*8];
            acc[0][j] = __builtin_amdgcn_mfma_f32_16x16x32_bf16(a0, bv, acc[0][j], 0,0,0);
            acc[1][j] = __builtin_amdgcn_mfma_f32_16x16x32_bf16(a1, bv, acc[1][j], 0,0,0);
        }
    }
    #pragma unroll
    for (int i = 0; i < 2; i++) {
        #pragma unroll
        for (int rr = 0; rr < 4; rr++) {
            int grow = m0 + w*32 + i*16 + fc*4 + rr;
            if (grow < M) {
                #pragma unroll
                for (int j = 0; j < 4; j++) {
                    float v = acc[i][j][rr];
                    long o = (long)grow*N + n0 + j*16 + fr;
                    if (SMODE != 2) C[o] = v;
                    if (SMODE != 0) C2[o] = (__bf16)v;
                }
            }
        }
    }
}

// ---------------------------------------------------------------------------
// bf16 MFMA GEMM (BM=128,BN=128,BK=64), bf16-out only. Used for in_proj.
// ---------------------------------------------------------------------------
__global__ __launch_bounds__(256) void gemm_bf16_128(
    const __bf16* __restrict__ A, const __bf16* __restrict__ W,
    __bf16* __restrict__ C2, int M, int N, int K)
{
    __shared__ __bf16 Als[128*AST2];
    __shared__ __bf16 Wls[128*AST2];
    const int tid = threadIdx.x;
    const int lane = tid & 63, w = tid >> 6;
    const int n0 = blockIdx.x*128, m0 = blockIdx.y*128;
    const int fr = lane & 15, fc = lane >> 4;
    const int row2 = tid >> 1, half = tid & 1;

    f32x4 acc[2][8] = {};

    for (int k0 = 0; k0 < K; k0 += 64) {
        bf16x8 av[4], wv[4];
        const bool aok = (m0 + row2) < M;
        const __bf16* asrc = A + (long)(m0+row2)*K + k0 + half*32;
        const __bf16* wsrc = W + (long)(n0+row2)*K + k0 + half*32;
        #pragma unroll
        for (int e = 0; e < 4; e++) {
            av[e] = aok ? *(const bf16x8*)(asrc + e*8) : (bf16x8){};
            wv[e] = *(const bf16x8*)(wsrc + e*8);
        }
        __syncthreads();
        #pragma unroll
        for (int e = 0; e < 4; e++) {
            *(bf16x8*)&Als[row2*AST2 + half*32 + e*8] = av[e];
            *(bf16x8*)&Wls[row2*AST2 + half*32 + e*8] = wv[e];
        }
        __syncthreads();
        #pragma unroll
        for (int s = 0; s < 2; s++) {
            bf16x8 a0 = *(const bf16x8*)&Als[(w*32 +      fr)*AST2 + s*32 + fc*8];
            bf16x8 a1 = *(const bf16x8*)&Als[(w*32 + 16 + fr)*AST2 + s*32 + fc*8];
            #pragma unroll
            for (int j = 0; j < 8; j++) {
                bf16x8 bv = *(const bf16x8*)&Wls[(j*16 + fr)*AST2 + s*32 + fc*8];
                acc[0][j] = __builtin_amdgcn_mfma_f32_16x16x32_bf16(a0, bv, acc[0][j], 0,0,0);
                acc[1][j] = __builtin_amdgcn_mfma_f32_16x16x32_bf16(a1, bv, acc[1][j], 0,0,0);
            }
        }
    }
    #pragma unroll
    for (int i = 0; i < 2; i++) {
        #pragma unroll
        for (int rr = 0; rr < 4; rr++) {
            int grow = m0 + w*32 + i*16 + fc*4 + rr;
            if (grow < M) {
                #pragma unroll
                for (int j = 0; j < 8; j++)
                    C2[(long)grow*N + n0 + j*16 + fr] = (__bf16)acc[i][j][rr];
            }
        }
    }
}

// ---------------------------------------------------------------------------
// dbc GEMM: dbc[M,48] = xib[M,512] @ Wx[48,512]^T.  BM=64, 128 threads
// ---------------------------------------------------------------------------
__global__ __launch_bounds__(128) void gemm_dbc(
    const __bf16* __restrict__ A, const __bf16* __restrict__ W,
    float* __restrict__ C, int M)
{
    __shared__ __bf16 Als[64*ASTR];
    __shared__ __bf16 Wls[48*ASTR];
    const int tid = threadIdx.x;
    const int lane = tid & 63, w = tid >> 6;
    const int m0 = blockIdx.x*64;
    f32x4 acc[2][3] = {};

    const int arow = tid >> 1, ahalf = tid & 1;
    const int fr = lane & 15, fc = lane >> 4;

    for (int k0 = 0; k0 < 512; k0 += 32) {
        bf16x8 av0 = {}, av1 = {};
        if (m0 + arow < M) {
            const __bf16* src = A + (long)(m0+arow)*512 + k0 + ahalf*16;
            av0 = *(const bf16x8*)src;
            av1 = *(const bf16x8*)(src+8);
        }
        bf16x8 wv0 = {}, wv1 = {};
        if (tid < 96) {
            const __bf16* src = W + (long)(tid>>1)*512 + k0 + (tid&1)*16;
            wv0 = *(const bf16x8*)src;
            wv1 = *(const bf16x8*)(src+8);
        }
        __syncthreads();
        *(bf16x8*)&Als[arow*ASTR + ahalf*16]     = av0;
        *(bf16x8*)&Als[arow*ASTR + ahalf*16 + 8] = av1;
        if (tid < 96) {
            *(bf16x8*)&Wls[(tid>>1)*ASTR + (tid&1)*16]     = wv0;
            *(bf16x8*)&Wls[(tid>>1)*ASTR + (tid&1)*16 + 8] = wv1;
        }
        __syncthreads();

        bf16x8 a0 = *(const bf16x8*)&Als[(w*32 +      fr)*ASTR + fc*8];
        bf16x8 a1 = *(const bf16x8*)&Als[(w*32 + 16 + fr)*ASTR + fc*8];
        #pragma unroll
        for (int j = 0; j < 3; j++) {
            bf16x8 bv = *(const bf16x8*)&Wls[(j*16 + fr)*ASTR + fc*8];
            acc[0][j] = __builtin_amdgcn_mfma_f32_16x16x32_bf16(a0, bv, acc[0][j], 0,0,0);
            acc[1][j] = __builtin_amdgcn_mfma_f32_16x16x32_bf16(a1, bv, acc[1][j], 0,0,0);
        }
    }
    #pragma unroll
    for (int i = 0; i < 2; i++) {
        #pragma unroll
        for (int rr = 0; rr < 4; rr++) {
            int grow = m0 + w*32 + i*16 + fc*4 + rr;
            if (grow < M) {
                #pragma unroll
                for (int j = 0; j < 3; j++)
                    C[(long)grow*48 + j*16 + fr] = acc[i][j][rr];
            }
        }
    }
}

// ---------------------------------------------------------------------------
// delta: softplus(dbc[:, :16] @ Wdt^T + bdt); pack (delta,xi) bf16 pair -> u32
// ---------------------------------------------------------------------------
__global__ __launch_bounds__(256) void delta_k(
    const float* __restrict__ dbc, const float* __restrict__ Wdt,
    const float* __restrict__ bdt, const __bf16* __restrict__ xib,
    unsigned* __restrict__ pdx)
{
    const int d0 = threadIdx.x, d1 = threadIdx.x + 256;
    const int r0 = blockIdx.x*8;
    f32x4 wa[4], wb[4];
    #pragma unroll
    for (int q = 0; q < 4; q++) {
        wa[q] = *(const f32x4*)(Wdt + d0*16 + q*4);
        wb[q] = *(const f32x4*)(Wdt + d1*16 + q*4);
    }
    const float b0 = bdt[d0], b1 = bdt[d1];
    #pragma unroll
    for (int rr = 0; rr < 8; rr++) {
        int row = r0 + rr;
        if (row >= ROWS) return;
        const f32x4* p = (const f32x4*)(dbc + (long)row*48);
        f32x4 t0 = p[0], t1 = p[1], t2 = p[2], t3 = p[3];
        float s0 = b0, s1 = b1;
        #pragma unroll
        for (int e = 0; e < 4; e++) {
            s0 += wa[0][e]*t0[e] + wa[1][e]*t1[e] + wa[2][e]*t2[e] + wa[3][e]*t3[e];
            s1 += wb[0][e]*t0[e] + wb[1][e]*t1[e] + wb[2][e]*t2[e] + wb[3][e]*t3[e];
        }
        float dl0 = (s0 > 20.f) ? s0 : log1pf(__expf(s0));
        float dl1 = (s1 > 20.f) ? s1 : log1pf(__expf(s1));
        unsigned x0 = __builtin_bit_cast(unsigned short, xib[(long)row*512 + d0]);
        unsigned x1 = __builtin_bit_cast(unsigned short, xib[(long)row*512 + d1]);
        pdx[(long)row*512 + d0] = (unsigned)bfbits(dl0) | (x0 << 16);
        pdx[(long)row*512 + d1] = (unsigned)bfbits(dl1) | (x1 << 16);
    }
}

// ---------------------------------------------------------------------------
// Patch rearrange + LayerNorm(256) + skip add; cls row q==0
// ---------------------------------------------------------------------------
__global__ __launch_bounds__(256) void rearrange_ln_cls(
    const __bf16* __restrict__ e_buf, const float* __restrict__ x,
    const float* __restrict__ cls_w, const float* __restrict__ cls_b,
    const float* __restrict__ ln_g, const float* __restrict__ ln_b,
    const float* __restrict__ skip, float* __restrict__ xx,
    __bf16* __restrict__ xxb)
{
    const int blk = blockIdx.x;
    const int b = blk / L_TOT;
    const int q = blk % L_TOT;
    const int c = threadIdx.x;

    if (q == 0) {
        __shared__ float xr[512];
        const float* xrow = x + (long)b*1025*512;
        xr[c] = xrow[c]; xr[c+256] = xrow[c+256];
        __syncthreads();
        float acc = cls_b[c];
        const float4* wrow = (const float4*)(cls_w + (long)c*512);
        #pragma unroll 8
        for (int m4 = 0; m4 < 128; m4++) {
            float4 wv = wrow[m4];
            float4 xv = *(const float4*)&xr[m4*4];
            acc += wv.x*xv.x + wv.y*xv.y + wv.z*xv.z + wv.w*xv.w;
        }
        long o = (long)b*L_TOT*256 + c;
        float v = acc + skip[o];
        xx[o] = v; xxb[o] = (__bf16)v;
        return;
    }
    const int t  = (q-1) >> 10;
    const int p  = (q-1) & 1023;
    const int h  = p >> 6;
    const int a  = (p >> 5) & 1;
    const int w  = (p >> 1) & 15;
    const int bb = p & 1;
    const long tok = (long)b*1024 + t*256 + h*16 + w;
    float v = (float)e_buf[tok*1024 + a*512 + bb*256 + c];

    float s = v, s2 = v*v;
    #pragma unroll
    for (int o = 32; o > 0; o >>= 1) { s += __shfl_xor(s, o); s2 += __shfl_xor(s2, o); }
    __shared__ float ps[4], ps2[4];
    __shared__ float mu_s, rs_s;
    const int wv = threadIdx.x >> 6;
    if ((threadIdx.x & 63) == 0) { ps[wv] = s; ps2[wv] = s2; }
    __syncthreads();
    if (threadIdx.x == 0) {
        float S = ps[0]+ps[1]+ps[2]+ps[3];
        float S2 = ps2[0]+ps2[1]+ps2[2]+ps2[3];
        float mu = S * (1.f/256.f);
        float var = S2 * (1.f/256.f) - mu*mu;
        mu_s = mu; rs_s = rsqrtf(var + 1e-5f);
    }
    __syncthreads();
    long o = ((long)b*L_TOT + q)*256 + c;
    float outv = (v - mu_s)*rs_s*ln_g[c] + ln_b[c] + skip[o];
    xx[o] = outv; xxb[o] = (__bf16)outv;
}

// ---------------------------------------------------------------------------
// Depthwise causal conv (k=4)+SiLU: thread = (8-chan chunk, 8-row block).
// Taps in registers, sliding window; z-half threads do silu(z).
// ---------------------------------------------------------------------------
__global__ __launch_bounds__(256) void conv_silu_split(
    const __bf16* __restrict__ xzb, const float* __restrict__ cw,
    const float* __restrict__ cb, __bf16* __restrict__ xib,
    __bf16* __restrict__ zsb)
{
    const int tid = threadIdx.x;
    const int c = tid & 127;                       // chunk
    const long r0 = ((long)blockIdx.x*2 + (tid >> 7))*8;
    if (r0 >= ROWS) return;

    if (c < 64) {
        const int d0 = c*8;
        float wreg[4][8], breg[8];
        #pragma unroll
        for (int e = 0; e < 8; e++) {
            breg[e] = cb[d0+e];
            #pragma unroll
            for (int k = 0; k < 4; k++) wreg[k][e] = cw[(d0+e)*4 + k];
        }
        bf16x8 win[4];
        #pragma unroll
        for (int j = 0; j < 3; j++) {
            long rr = r0 - 3 + j;
            win[j] = (rr >= 0) ? *(const bf16x8*)&xzb[rr*1024 + d0] : (bf16x8){};
        }
        #pragma unroll
        for (int rr = 0; rr < 8; rr++) {
            long rl = r0 + rr;
            if (rl >= ROWS) break;
            win[3] = *(const bf16x8*)&xzb[rl*1024 + d0];
            int l = (int)(rl % L_TOT);
            float acc[8];
            #pragma unroll
            for (int e = 0; e < 8; e++) acc[e] = breg[e];
            #pragma unroll
            for (int k = 0; k < 4; k++) {
                if (l + k - 3 >= 0) {
                    #pragma unroll
                    for (int e = 0; e < 8; e++)
                        acc[e] += wreg[k][e]*(float)win[k][e];
                }
            }
            bf16x8 o;
            #pragma unroll
            for (int e = 0; e < 8; e++) o[e] = (__bf16)siluf_(acc[e]);
            *(bf16x8*)&xib[rl*512 + d0] = o;
            win[0] = win[1]; win[1] = win[2]; win[2] = win[3];
        }
    } else {
        const int d0 = (c - 64)*8;
        #pragma unroll
        for (int rr = 0; rr < 8; rr++) {
            long rl = r0 + rr;
            if (rl >= ROWS) break;
            bf16x8 v = *(const bf16x8*)&xzb[rl*1024 + 512 + d0];
            bf16x8 o;
            #pragma unroll
            for (int e = 0; e < 8; e++) o[e] = (__bf16)siluf_((float)v[e]);
            *(bf16x8*)&zsb[rl*512 + d0] = o;
        }
    }
}

// ---------------------------------------------------------------------------
// Segmented scan, LDS-staged. Block = (seg, b, 64-d group); 256 thr = 64d x 4ng
// ---------------------------------------------------------------------------
__global__ __launch_bounds__(256) void scan_p1(
    const unsigned* __restrict__ pdx,
    const float* __restrict__ dbc, const float* __restrict__ A_log,
    float* __restrict__ segH, float* __restrict__ segP)
{
    __shared__ unsigned pdxS[SEGLEN*64];
    __shared__ float bS[SEGLEN*16];
    const int blk = blockIdx.x;
    const int seg = blk >> 4;
    const int b   = (blk >> 3) & 1;
    const int dbase = (blk & 7)*64;
    const int tid = threadIdx.x;
    const int l0 = seg*SEGLEN;
    const int nl = min(l0 + SEGLEN, L_TOT) - l0;
    const int nlc = nl > 0 ? nl : 0;

    for (int cc = tid; cc < nlc*16; cc += 256) {
        int l = cc >> 4, qq = cc & 15;
        *(uint4*)&pdxS[l*64 + qq*4] =
            *(const uint4*)&pdx[((long)b*L_TOT + l0 + l)*512 + dbase + qq*4];
    }
    for (int cc = tid; cc < nlc*4; cc += 256) {
        int l = cc >> 2, qq = cc & 3;
        *(f32x4*)&bS[l*16 + qq*4] =
            *(const f32x4*)&dbc[((long)b*L_TOT + l0 + l)*48 + 16 + qq*4];
    }
    __syncthreads();

    const int dl_ = tid >> 2;            // 0..63 within group
    const int d = dbase + dl_;
    const int ng = tid & 3;
    f32x4 Al = *(const f32x4*)(A_log + d*16 + ng*4);
    float Ar[4] = {-__expf(Al[0]), -__expf(Al[1]), -__expf(Al[2]), -__expf(Al[3])};
    float h[4] = {0,0,0,0};
    float P[4] = {1,1,1,1};
    for (int l = 0; l < nlc; l++) {
        unsigned v = pdxS[l*64 + dl_];
        float dl = __uint_as_float(v << 16);
        float xv = __uint_as_float(v & 0xffff0000u);
        f32x4 Bv = *(const f32x4*)&bS[l*16 + ng*4];
        float dx = dl*xv;
        #pragma unroll
        for (int n = 0; n < 4; n++) {
            float E = __expf(dl*Ar[n]);
            h[n] = h[n]*E + dx*Bv[n];
            P[n] *= E;
        }
    }
    long off = ((long)(seg*2 + b)*512 + d)*16 + ng*4;
    *(f32x4*)&segH[off] = f32x4{h[0],h[1],h[2],h[3]};
    *(f32x4*)&segP[off] = f32x4{P[0],P[1],P[2],P[3]};
}

__global__ __launch_bounds__(256) void scan_p2(
    float* __restrict__ segH, const float* __restrict__ segP)
{
    const int idx = blockIdx.x*256 + threadIdx.x;   // 16384
    float carry = 0.f;
    for (int s0 = 0; s0 < NSEG; s0 += 8) {
        float hh[8], pp[8];
        #pragma unroll
        for (int j = 0; j < 8; j++) {
            long o = (long)(s0+j)*16384 + idx;
            hh[j] = segH[o]; pp[j] = segP[o];
        }
        #pragma unroll
        for (int j = 0; j < 8; j++) {
            long o = (long)(s0+j)*16384 + idx;
            segH[o] = carry;
            carry = pp[j]*carry + hh[j];
        }
    }
}

__global__ __launch_bounds__(256) void scan_p3(
    const unsigned* __restrict__ pdx,
    const float* __restrict__ dbc, const float* __restrict__ A_log,
    const float* __restrict__ segH, const float* __restrict__ Dp,
    const __bf16* __restrict__ zsb, __bf16* __restrict__ yb)
{
    __shared__ unsigned pdxS[SEGLEN*64];
    __shared__ float bcS[SEGLEN*32];
    __shared__ __bf16 zS[SEGLEN*64];
    __shared__ __bf16 yS[SEGLEN*64];
    const int blk = blockIdx.x;
    const int seg = blk >> 4;
    const int b   = (blk >> 3) & 1;
    const int dbase = (blk & 7)*64;
    const int tid = threadIdx.x;
    const int l0 = seg*SEGLEN;
    const int nl = min(l0 + SEGLEN, L_TOT) - l0;
    const int nlc = nl > 0 ? nl : 0;
    if (nlc == 0) return;

    for (int cc = tid; cc < nlc*16; cc += 256) {
        int l = cc >> 4, qq = cc & 15;
        *(uint4*)&pdxS[l*64 + qq*4] =
            *(const uint4*)&pdx[((long)b*L_TOT + l0 + l)*512 + dbase + qq*4];
    }
    for (int cc = tid; cc < nlc*8; cc += 256) {
        int l = cc >> 3, qq = cc & 7;
        *(f32x4*)&bcS[l*32 + qq*4] =
            *(const f32x4*)&dbc[((long)b*L_TOT + l0 + l)*48 + 16 + qq*4];
    }
    for (int cc = tid; cc < nlc*8; cc += 256) {
        int l = cc >> 3, qq = cc & 7;
        *(bf16x8*)&zS[l*64 + qq*8] =
            *(const bf16x8*)&zsb[((long)b*L_TOT + l0 + l)*512 + dbase + qq*8];
    }
    __syncthreads();

    const int dl_ = tid >> 2;
    const int d = dbase + dl_;
    const int ng = tid & 3;
    f32x4 Al = *(const f32x4*)(A_log + d*16 + ng*4);
    float Ar[4] = {-__expf(Al[0]), -__expf(Al[1]), -__expf(Al[2]), -__expf(Al[3])};
    long off = ((long)(seg*2 + b)*512 + d)*16 + ng*4;
    f32x4 h4 = *(const f32x4*)&segH[off];
    float h[4] = {h4[0], h4[1], h4[2], h4[3]};
    const float Dd = Dp[d];
    for (int l = 0; l < nlc; l++) {
        unsigned v = pdxS[l*64 + dl_];
        float dl = __uint_as_float(v << 16);
        float xv = __uint_as_float(v & 0xffff0000u);
        f32x4 Bv = *(const f32x4*)&bcS[l*32 + ng*4];
        f32x4 Cv = *(const f32x4*)&bcS[l*32 + 16 + ng*4];
        float dx = dl*xv;
        float y = 0.f;
        #pragma unroll
        for (int n = 0; n < 4; n++) {
            float E = __expf(dl*Ar[n]);
            h[n] = h[n]*E + dx*Bv[n];
            y += h[n]*Cv[n];
        }
        y += __shfl_xor(y, 1);
        y += __shfl_xor(y, 2);
        if (ng == 0) {
            float z = (float)zS[l*64 + dl_];
            yS[l*64 + dl_] = (__bf16)((y + xv*Dd)*z);
        }
    }
    __syncthreads();
    for (int cc = tid; cc < nlc*8; cc += 256) {
        int l = cc >> 3, qq = cc & 7;
        *(bf16x8*)&yb[((long)b*L_TOT + l0 + l)*512 + dbase + qq*8] =
            *(bf16x8*)&yS[l*64 + qq*8];
    }
}

// ---------------------------------------------------------------------------
// BatchNorm over rows
// ---------------------------------------------------------------------------
__global__ void zero_stats(float* __restrict__ stats) { stats[threadIdx.x] = 0.f; }

__global__ __launch_bounds__(256) void bn_reduce(
    const float* __restrict__ xx, float* __restrict__ stats)
{
    const int c = threadIdx.x;
    float s = 0.f, s2 = 0.f;
    for (int r = blockIdx.x; r < ROWS; r += gridDim.x) {
        float v = xx[(long)r*256 + c];
        s += v; s2 += v*v;
    }
    atomicAdd(&stats[c], s);
    atomicAdd(&stats[256 + c], s2);
}

__global__ __launch_bounds__(256) void bn_apply(
    const float* __restrict__ xx, const float* __restrict__ stats,
    const float* __restrict__ g, const float* __restrict__ bta,
    float* __restrict__ out)
{
    long idx = (long)blockIdx.x*256 + threadIdx.x;
    if (idx == 0) out[(long)ROWS*256] = 1024.0f;
    if (idx >= (long)ROWS*256) return;
    int c = (int)(idx & 255);
    float mu = stats[c] * (1.f/ROWS);
    float var = stats[256 + c] * (1.f/ROWS) - mu*mu;
    out[idx] = (xx[idx] - mu)*rsqrtf(var + 1e-5f)*g[c] + bta[c];
}

// ---------------------------------------------------------------------------
extern "C" void kernel_launch(void* const* d_in, const int* in_sizes, int n_in,
                              void* d_out, int out_size, void* d_ws, size_t ws_size,
                              hipStream_t stream)
{
    const float* x        = (const float*)d_in[0];
    const float* skip     = (const float*)d_in[1];
    const float* exp_w    = (const float*)d_in[2];
    const float* ln_g     = (const float*)d_in[3];
    const float* ln_b     = (const float*)d_in[4];
    const float* cls_w    = (const float*)d_in[5];
    const float* cls_b    = (const float*)d_in[6];
    const float* in_proj_w= (const float*)d_in[7];
    const float* conv_w   = (const float*)d_in[8];
    const float* conv_b   = (const float*)d_in[9];
    const float* xproj_w  = (const float*)d_in[10];
    const float* dt_w     = (const float*)d_in[11];
    const float* dt_b     = (const float*)d_in[12];
    const float* A_log    = (const float*)d_in[13];
    const float* Dp       = (const float*)d_in[14];
    const float* out_w    = (const float*)d_in[15];
    const float* bn_g     = (const float*)d_in[16];
    const float* bn_b     = (const float*)d_in[17];

    float* ws = (float*)d_ws;
    float* xx    = ws;                       // 2,097,664 f32
    float* dbc   = xx + 2097664;             //   393,312 f32
    float* segH  = dbc + 393312;             // 2,097,152 f32
    float* segP  = segH + 2097152;           // 2,097,152 f32
    float* stats = segP + 2097152;           //       512 f32
    unsigned* pdx = (unsigned*)(stats + 512);// 4,195,328 u32
    __bf16* expWb = (__bf16*)(pdx + 4195328);//   524,288
    __bf16* inWb  = expWb + 524288;          //   524,288
    __bf16* outWb = inWb + 524288;           //   262,144
    __bf16* xpWb  = outWb + 262144;          //    49,152
    __bf16* xxb   = xpWb + 49152;            // 2,097,664
    __bf16* xzb   = xxb + 2097664;           // 8,390,656
    __bf16* e_b   = xzb;                     // alias (pre-loop)
    __bf16* xib   = xzb + 8390656;           // 4,195,328
    __bf16* Axb   = xib;                     // alias (pre-loop)
    __bf16* zsb   = xib + 4195328;           // 4,195,328
    __bf16* yb    = zsb + 4195328;           // 4,195,328
    float* out    = (float*)d_out;

    cvt4<<<(1359872/8 + 255)/256, 256, 0, stream>>>(
        exp_w, in_proj_w, out_w, xproj_w, expWb, inWb, outWb, xpWb);
    cvt_gather_x<<<(1048576/8)/256, 256, 0, stream>>>(x, Axb);

    gemm_bf16<2><<<dim3(16, 16), 256, 0, stream>>>(
        Axb, expWb, nullptr, e_b, 2048, 1024, 512);
    rearrange_ln_cls<<<ROWS, 256, 0, stream>>>(
        e_b, x, cls_w, cls_b, ln_g, ln_b, skip, xx, xxb);

    for (int layer = 0; layer < 2; layer++) {
        gemm_bf16_128<<<dim3(8, 65), 256, 0, stream>>>(
            xxb, inWb + layer*262144, xzb, ROWS, 1024, 256);
        conv_silu_split<<<513, 256, 0, stream>>>(
            xzb, conv_w + layer*512*4, conv_b + layer*512, xib, zsb);
        gemm_dbc<<<(ROWS + 63)/64, 128, 0, stream>>>(
            xib, xpWb + layer*24576, dbc, ROWS);
        delta_k<<<(ROWS + 7)/8, 256, 0, stream>>>(
            dbc, dt_w + layer*512*16, dt_b + layer*512, xib, pdx);
        scan_p1<<<NSEG*16, 256, 0, stream>>>(
            pdx, dbc, A_log + layer*512*16, segH, segP);
        scan_p2<<<64, 256, 0, stream>>>(segH, segP);
        scan_p3<<<NSEG*16, 256, 0, stream>>>(
            pdx, dbc, A_log + layer*512*16, segH, Dp + layer*512, zsb, yb);
        if (layer == 0) {
            gemm_bf16<1><<<dim3(4, 65), 256, 0, stream>>>(
                yb, outWb, xx, xxb, ROWS, 256, 512);
        } else {
            gemm_bf16<0><<<dim3(4, 65), 256, 0, stream>>>(
                yb, outWb + 131072, xx, nullptr, ROWS, 256, 512);
        }
    }

    zero_stats<<<1, 512, 0, stream>>>(stats);
    bn_reduce<<<128, 256, 0, stream>>>(xx, stats);
    bn_apply<<<((long)ROWS*256 + 255)/256 + 1, 256, 0, stream>>>(xx, stats, bn_g, bn_b, out);
}